// Round 8
// baseline (1340.889 us; speedup 1.0000x reference)
//
#include <hip/hip_runtime.h>
#include <math.h>

#define DM 3136
#define DH 512

#define MICRO_4x4 \
    acc[0][0] += a.x*b.x; acc[0][1] += a.x*b.y; acc[0][2] += a.x*b.z; acc[0][3] += a.x*b.w; \
    acc[1][0] += a.y*b.x; acc[1][1] += a.y*b.y; acc[1][2] += a.y*b.z; acc[1][3] += a.y*b.w; \
    acc[2][0] += a.z*b.x; acc[2][1] += a.z*b.y; acc[2][2] += a.z*b.z; acc[2][3] += a.z*b.w; \
    acc[3][0] += a.w*b.x; acc[3][1] += a.w*b.y; acc[3][2] += a.w*b.z; acc[3][3] += a.w*b.w;

// ---- last-block-arrives: release by every block, acquire by the unique winner ----
__device__ __forceinline__ bool last_arrive(unsigned* cnt, unsigned n) {
  __shared__ unsigned sflag;
  __syncthreads();
  if (threadIdx.x == 0) {
    unsigned old = __hip_atomic_fetch_add(cnt, 1u, __ATOMIC_RELEASE, __HIP_MEMORY_SCOPE_AGENT);
    if (old == n - 1u) {
      (void)__hip_atomic_exchange(cnt, 0u, __ATOMIC_ACQUIRE, __HIP_MEMORY_SCOPE_AGENT);
      sflag = 1;
    } else sflag = 0;
  }
  __syncthreads();
  return sflag != 0;
}

// ---------------- gelu ----------------
__device__ __forceinline__ void gelu_both(float xx, float& g, float& gp) {
  const float c = 0.7978845608028654f;
  const float a = 0.044715f;
  float x2 = xx * xx;
  float u = c * (xx + a * xx * x2);
  float t = tanhf(u);
  g  = 0.5f * xx * (1.f + t);
  gp = 0.5f * (1.f + t) + 0.5f * xx * (1.f - t * t) * c * (1.f + 3.f * a * x2);
}
__device__ __forceinline__ float gelu_only(float xx) {
  const float c = 0.7978845608028654f;
  const float a = 0.044715f;
  float u = c * (xx + a * xx * xx * xx);
  return 0.5f * xx * (1.f + tanhf(u));
}

// ---------------- conv3x3 + RMSNorm (proven R2) ----------------
__global__ __launch_bounds__(256) void conv_rms(
    const float* __restrict__ x,
    const float* __restrict__ wk, const float* __restrict__ bk,
    const float* __restrict__ wv, const float* __restrict__ bv,
    const float* __restrict__ sk, const float* __restrict__ sv,
    float* __restrict__ nk, float* __restrict__ nv) {
  __shared__ float swk[144], swv[144], sb[16];
  int tid = threadIdx.x;
  if (tid < 144) { swk[tid] = wk[tid]; swv[tid] = wv[tid]; }
  if (tid < 4) {
    sb[tid] = bk[tid]; sb[4 + tid] = bv[tid];
    sb[8 + tid] = sk[tid]; sb[12 + tid] = sv[tid];
  }
  __syncthreads();
  int idx = blockIdx.x * 256 + tid;
  int t = idx / 784, hw = idx - t * 784;
  int h = hw / 28, w = hw - h * 28;
  float ak[4], av[4];
  #pragma unroll
  for (int c = 0; c < 4; ++c) { ak[c] = sb[c]; av[c] = sb[4 + c]; }
  const float* xt = x + (size_t)t * DM;
  for (int kh = 0; kh < 3; ++kh) {
    int ih = h + kh - 1;
    if (ih < 0 || ih >= 28) continue;
    for (int kw = 0; kw < 3; ++kw) {
      int iw = w + kw - 1;
      if (iw < 0 || iw >= 28) continue;
      int base = (kh * 3 + kw) * 16;
      #pragma unroll
      for (int ci = 0; ci < 4; ++ci) {
        float xv = xt[ci * 784 + ih * 28 + iw];
        #pragma unroll
        for (int co = 0; co < 4; ++co) {
          ak[co] += xv * swk[base + ci * 4 + co];
          av[co] += xv * swv[base + ci * 4 + co];
        }
      }
    }
  }
  float mk = (ak[0]*ak[0] + ak[1]*ak[1] + ak[2]*ak[2] + ak[3]*ak[3]) * 0.25f + 1e-6f;
  float mv = (av[0]*av[0] + av[1]*av[1] + av[2]*av[2] + av[3]*av[3]) * 0.25f + 1e-6f;
  float ik = 1.f / sqrtf(mk), iv = 1.f / sqrtf(mv);
  float4 ok = { ak[0]*ik*sb[8],  ak[1]*ik*sb[9],  ak[2]*ik*sb[10], ak[3]*ik*sb[11] };
  float4 ov = { av[0]*iv*sb[12], av[1]*iv*sb[13], av[2]*iv*sb[14], av[3]*iv*sb[15] };
  *(float4*)&nk[(size_t)idx * 4] = ok;
  *(float4*)&nv[(size_t)idx * 4] = ov;
}

// ---------------- device GEMM bodies (proven R7) ----------------
__device__ __forceinline__ void mm_nn_slice(
    const float* __restrict__ A, int lda, const float* __restrict__ B, int ldb,
    float* __restrict__ Cp, int ldc, int n_t, int k_t, float* smem) {
  float* As = smem;
  float* Bs = smem + 4096;
  int tid = threadIdx.x;
  int n0 = n_t * 64, k0 = k_t * 64;
  {
    int m  = tid >> 2;
    int kb = (tid & 3) * 16;
    const float* Ap = A + (size_t)m * lda + k0 + kb;
    #pragma unroll
    for (int q = 0; q < 4; ++q) {
      float4 v = *(const float4*)(Ap + q * 4);
      As[(kb + q*4 + 0)*64 + m] = v.x;
      As[(kb + q*4 + 1)*64 + m] = v.y;
      As[(kb + q*4 + 2)*64 + m] = v.z;
      As[(kb + q*4 + 3)*64 + m] = v.w;
    }
    int kr = tid >> 4;
    int nn = (tid & 15) * 4;
    #pragma unroll
    for (int q = 0; q < 4; ++q)
      *(float4*)&Bs[(kr + q*16)*64 + nn] = *(const float4*)(B + (size_t)(k0 + kr + q*16) * ldb + n0 + nn);
  }
  __syncthreads();
  int tx = tid & 15, ty = tid >> 4;
  float acc[4][4] = {{0.f}};
  #pragma unroll 16
  for (int kk = 0; kk < 64; ++kk) {
    float4 a = *(const float4*)&As[kk*64 + ty * 4];
    float4 b = *(const float4*)&Bs[kk*64 + tx * 4];
    MICRO_4x4
  }
  float* Cb = Cp + (size_t)k_t * 64 * ldc + n0 + tx * 4;
  #pragma unroll
  for (int r = 0; r < 4; ++r) {
    float4 v = { acc[r][0], acc[r][1], acc[r][2], acc[r][3] };
    *(float4*)&Cb[(size_t)(ty * 4 + r) * ldc] = v;
  }
}

__device__ __forceinline__ void mm_nt_slice(
    const float* __restrict__ A, int lda, const float* __restrict__ B, int ldb,
    float* __restrict__ Cp, int ldc, int n_t, int k_t, float* smem) {
  float* As = smem;
  float* Bs = smem + 4096;
  int tid = threadIdx.x;
  int n0 = n_t * 64, k0 = k_t * 64;
  {
    int m  = tid >> 2;
    int kb = (tid & 3) * 16;
    const float* Ap = A + (size_t)m * lda + k0 + kb;
    const float* Bp = B + (size_t)(n0 + m) * ldb + k0 + kb;
    #pragma unroll
    for (int q = 0; q < 4; ++q) {
      float4 va = *(const float4*)(Ap + q * 4);
      As[(kb + q*4 + 0)*64 + m] = va.x;
      As[(kb + q*4 + 1)*64 + m] = va.y;
      As[(kb + q*4 + 2)*64 + m] = va.z;
      As[(kb + q*4 + 3)*64 + m] = va.w;
      float4 vb = *(const float4*)(Bp + q * 4);
      Bs[(kb + q*4 + 0)*64 + m] = vb.x;
      Bs[(kb + q*4 + 1)*64 + m] = vb.y;
      Bs[(kb + q*4 + 2)*64 + m] = vb.z;
      Bs[(kb + q*4 + 3)*64 + m] = vb.w;
    }
  }
  __syncthreads();
  int tx = tid & 15, ty = tid >> 4;
  float acc[4][4] = {{0.f}};
  #pragma unroll 16
  for (int kk = 0; kk < 64; ++kk) {
    float4 a = *(const float4*)&As[kk*64 + ty * 4];
    float4 b = *(const float4*)&Bs[kk*64 + tx * 4];
    MICRO_4x4
  }
  float* Cb = Cp + (size_t)k_t * 64 * ldc + n0 + tx * 4;
  #pragma unroll
  for (int r = 0; r < 4; ++r) {
    float4 v = { acc[r][0], acc[r][1], acc[r][2], acc[r][3] };
    *(float4*)&Cb[(size_t)(ty * 4 + r) * ldc] = v;
  }
}

__device__ __forceinline__ void upd64_dev(
    const float* __restrict__ A, int P,
    const float* __restrict__ B, int Q,
    const float* __restrict__ Cold, float* __restrict__ Cnew,
    int bx, int by, float* smem) {
  float* As = smem;
  float* Bs = smem + 4096;
  int tid = threadIdx.x;
  int q0 = bx * 64;
  int p0 = by * 64;
  {
    int i = tid >> 4;
    int c = (tid & 15) * 4;
    #pragma unroll
    for (int q = 0; q < 4; ++q) {
      *(float4*)&As[(i + q*16)*64 + c] = *(const float4*)(A + (size_t)(i + q*16) * P + p0 + c);
      *(float4*)&Bs[(i + q*16)*64 + c] = *(const float4*)(B + (size_t)(i + q*16) * Q + q0 + c);
    }
  }
  __syncthreads();
  int tx = tid & 15, ty = tid >> 4;
  float acc[4][4] = {{0.f}};
  #pragma unroll 16
  for (int i = 0; i < 64; ++i) {
    float4 a = *(const float4*)&As[i*64 + ty * 4];
    float4 b = *(const float4*)&Bs[i*64 + tx * 4];
    MICRO_4x4
  }
  #pragma unroll
  for (int r = 0; r < 4; ++r) {
    size_t off = (size_t)(p0 + ty*4 + r) * Q + q0 + tx*4;
    float4 co = *(const float4*)&Cold[off];
    float4 v = { co.x - acc[r][0], co.y - acc[r][1], co.z - acc[r][2], co.w - acc[r][3] };
    *(float4*)&Cnew[off] = v;
  }
}

// ---------------- u1: KK + Hbase slices with winner-reduce tails ----------------
__device__ __forceinline__ void kk_slice(int p, int s, const float* __restrict__ nk,
                                         float* __restrict__ KKsl, float* smem) {
  float* As = smem;
  float* Bs = smem + 4096;
  int tid = threadIdx.x;
  int c = 0;
  while ((c + 1) * (c + 2) / 2 <= p) ++c;
  int j = p - c * (c + 1) / 2;
  const float* A = nk + (size_t)c * 64 * DM;
  const float* B = nk + (size_t)j * 64 * DM;
  int k0 = s * 64;
  {
    int m  = tid >> 2;
    int kb = (tid & 3) * 16;
    const float* Ap = A + (size_t)m * DM + k0 + kb;
    const float* Bp = B + (size_t)m * DM + k0 + kb;
    #pragma unroll
    for (int q = 0; q < 4; ++q) {
      float4 va = *(const float4*)(Ap + q * 4);
      As[(kb + q*4 + 0)*64 + m] = va.x;
      As[(kb + q*4 + 1)*64 + m] = va.y;
      As[(kb + q*4 + 2)*64 + m] = va.z;
      As[(kb + q*4 + 3)*64 + m] = va.w;
      float4 vb = *(const float4*)(Bp + q * 4);
      Bs[(kb + q*4 + 0)*64 + m] = vb.x;
      Bs[(kb + q*4 + 1)*64 + m] = vb.y;
      Bs[(kb + q*4 + 2)*64 + m] = vb.z;
      Bs[(kb + q*4 + 3)*64 + m] = vb.w;
    }
  }
  __syncthreads();
  int tx = tid & 15, ty = tid >> 4;
  float acc[4][4] = {{0.f}};
  #pragma unroll 16
  for (int kk = 0; kk < 64; ++kk) {
    float4 a = *(const float4*)&As[kk*64 + ty * 4];
    float4 b = *(const float4*)&Bs[kk*64 + tx * 4];
    MICRO_4x4
  }
  float* dst = KKsl + ((size_t)p * 49 + s) * 4096;
  #pragma unroll
  for (int r = 0; r < 4; ++r) {
    float4 v = { acc[r][0], acc[r][1], acc[r][2], acc[r][3] };
    *(float4*)&dst[(ty*4 + r) * 64 + tx*4] = v;
  }
}

__global__ __launch_bounds__(256) void u1_kernel(
    const float* __restrict__ nk, const float* __restrict__ W1,
    float* __restrict__ KKsl, float* __restrict__ Hb_sl,
    float* __restrict__ KKf, float* __restrict__ Hbase,
    unsigned* __restrict__ cntk, unsigned* __restrict__ cnth) {
  __shared__ float smem[8192];
  int job = blockIdx.x;
  int tid = threadIdx.x;
  if (job < 1764) {
    int p = job / 49, s = job % 49;
    kk_slice(p, s, nk, KKsl, smem);
    if (last_arrive(&cntk[p], 49)) {
      #pragma unroll
      for (int q = 0; q < 16; ++q) {
        int e = q * 256 + tid;
        float sum = 0.f;
        for (int t = 0; t < 49; ++t) sum += KKsl[((size_t)p * 49 + t) * 4096 + e];
        KKf[(size_t)p * 4096 + e] = sum;
      }
    }
  } else {
    int jb = job - 1764;
    int s  = jb % 49;
    int nt = (jb / 49) % 8;
    int mt = jb / 392;
    // Hbase slice: A = nk rows m0.., B = W1, write Hb_sl[s]
    mm_nn_slice(nk + (size_t)mt * 64 * DM, DM, W1, DH,
                Hb_sl + (size_t)(mt * 8 + nt) * 0 /*unused*/ , 0, 0, 0, smem); // placeholder never used
  }
}

// NOTE: mm_nn_slice writes via k_t*64*ldc which doesn't fit Hb layout; use dedicated body below.

__global__ __launch_bounds__(256) void u1b_kernel(
    const float* __restrict__ nkA, const float* __restrict__ W1,
    float* __restrict__ Hb_sl, float* __restrict__ Hbase,
    unsigned* __restrict__ cnth) {
  __shared__ float smem[8192];
  float* As = smem;
  float* Bs = smem + 4096;
  int tid = threadIdx.x;
  int jb = blockIdx.x;
  int s  = jb % 49;
  int nt = (jb / 49) % 8;
  int mt = jb / 392;
  int n0 = nt * 64;
  int m0 = mt * 64;
  int k0 = s * 64;
  {
    int m  = tid >> 2;
    int kb = (tid & 3) * 16;
    const float* Ap = nkA + (size_t)(m0 + m) * DM + k0 + kb;
    #pragma unroll
    for (int q = 0; q < 4; ++q) {
      float4 v = *(const float4*)(Ap + q * 4);
      As[(kb + q*4 + 0)*64 + m] = v.x;
      As[(kb + q*4 + 1)*64 + m] = v.y;
      As[(kb + q*4 + 2)*64 + m] = v.z;
      As[(kb + q*4 + 3)*64 + m] = v.w;
    }
    int kr = tid >> 4;
    int nn = (tid & 15) * 4;
    #pragma unroll
    for (int q = 0; q < 4; ++q)
      *(float4*)&Bs[(kr + q*16)*64 + nn] = *(const float4*)(W1 + (size_t)(k0 + kr + q*16) * DH + n0 + nn);
  }
  __syncthreads();
  int tx = tid & 15, ty = tid >> 4;
  float acc[4][4] = {{0.f}};
  #pragma unroll 16
  for (int kk = 0; kk < 64; ++kk) {
    float4 a = *(const float4*)&As[kk*64 + ty * 4];
    float4 b = *(const float4*)&Bs[kk*64 + tx * 4];
    MICRO_4x4
  }
  float* dst = Hb_sl + (size_t)s * 262144;
  #pragma unroll
  for (int r = 0; r < 4; ++r) {
    float4 v = { acc[r][0], acc[r][1], acc[r][2], acc[r][3] };
    *(float4*)&dst[(size_t)(m0 + ty*4 + r) * 512 + n0 + tx*4] = v;
  }
  if (last_arrive(&cnth[mt * 8 + nt], 49)) {
    #pragma unroll
    for (int q = 0; q < 16; ++q) {
      int e = q * 256 + tid;
      int r = e >> 6, c = e & 63;
      size_t idx = (size_t)(m0 + r) * 512 + n0 + c;
      float sum = 0.f;
      for (int t = 0; t < 49; ++t) sum += Hb_sl[(size_t)t * 262144 + idx];
      Hbase[idx] = sum;
    }
  }
}

// ---------------- hred body ----------------
__device__ __forceinline__ void hred_body(
    int j, const float* __restrict__ Hb_c, const float* __restrict__ Hcorr, int nsl,
    const float* __restrict__ b1v,
    float* __restrict__ H, float* __restrict__ G, float* __restrict__ Gp) {
  float s = Hb_c[j];
  for (int t = 0; t < nsl; ++t) s -= Hcorr[(size_t)t * 32768 + j];
  H[j] = s;
  float g, gp;
  gelu_both(s + b1v[j & 511], g, gp);
  G[j] = g; Gp[j] = gp;
}

__global__ __launch_bounds__(256) void hred0_kernel(
    const float* __restrict__ Hbase, const float* __restrict__ b1,
    float* __restrict__ H, float* __restrict__ G, float* __restrict__ Gp) {
  int j = blockIdx.x * 256 + threadIdx.x;
  hred_body(j, Hbase, (const float*)nullptr, 0, b1, H, G, Gp);
}

// ---------------- D1: P3 GEMM + winner (Dw, b2 update) ----------------
__global__ __launch_bounds__(256) void d1_kernel(
    const float* __restrict__ G, const float* __restrict__ W2c,
    const float* __restrict__ V, const float* __restrict__ b2c,
    float* __restrict__ Sp, float* __restrict__ Dw, float* __restrict__ b2n,
    unsigned* __restrict__ cnt, float wc2) {
  __shared__ float smem[8192];
  int b = blockIdx.x;
  int tid = threadIdx.x;
  int n_t = b % 49, k_t = b / 49;
  mm_nn_slice(G, DH, W2c, DM, Sp, DM, n_t, k_t, smem);
  if (last_arrive(&cnt[n_t], 8)) {
    int n0 = n_t * 64;
    int col = n0 + (tid & 63);
    int r0 = (tid >> 6) * 16;
    float bb = b2c[col];
    float cs = 0.f;
    for (int rr = 0; rr < 16; ++rr) {
      size_t off = (size_t)(r0 + rr) * DM + col;
      float s = 0.f;
      #pragma unroll
      for (int t = 0; t < 8; ++t) s += Sp[(size_t)t * 200704 + off];
      float d = wc2 * (s + bb - V[off]);
      Dw[off] = d;
      cs += d;
    }
    smem[tid] = cs;
    __syncthreads();
    if (tid < 64) {
      float tot = smem[tid] + smem[tid + 64] + smem[tid + 128] + smem[tid + 192];
      b2n[n0 + tid] = b2c[n0 + tid] - tot;
    }
  }
}

// ---------------- D2: P4 nt-GEMM || W2 update + winner (Ew, b1 update) ----------------
__global__ __launch_bounds__(256) void d2_kernel(
    const float* __restrict__ Dw, const float* __restrict__ W2c,
    const float* __restrict__ G, float* __restrict__ Sp,
    float* __restrict__ W2n, const float* __restrict__ Gp,
    float* __restrict__ Ew, const float* __restrict__ b1c, float* __restrict__ b1n,
    unsigned* __restrict__ cnt) {
  __shared__ float smem[8192];
  int b = blockIdx.x;
  int tid = threadIdx.x;
  if (b < 392) {
    int n_t = b & 7, k_t = b >> 3;
    mm_nt_slice(Dw, DM, W2c, DM, Sp, DH, n_t, k_t, smem);
    if (last_arrive(&cnt[n_t], 49)) {
      int n0 = n_t * 64;
      int col = n0 + (tid & 63);
      int r0 = (tid >> 6) * 16;
      float cs = 0.f;
      for (int rr = 0; rr < 16; ++rr) {
        int row = r0 + rr;
        float s = 0.f;
        for (int sl = 0; sl < 49; ++sl) s += Sp[(size_t)sl * 32768 + row * 512 + col];
        float ew = s * Gp[row * 512 + col];
        Ew[row * 512 + col] = ew;
        cs += ew;
      }
      smem[tid] = cs;
      __syncthreads();
      if (tid < 64) {
        float tot = smem[tid] + smem[tid + 64] + smem[tid + 128] + smem[tid + 192];
        b1n[n0 + tid] = b1c[n0 + tid] - tot;
      }
    }
  } else {
    int li = b - 392;
    upd64_dev(G, DH, Dw, DM, W2c, W2n, li % 49, li / 49, smem);
  }
}

// ---------------- D3: g2h (proven R7) ----------------
__device__ __forceinline__ void gelu2k_job(
    const float* __restrict__ KKcc, const float* __restrict__ Ew,
    const float* __restrict__ H, const float* __restrict__ b1n,
    float* __restrict__ G2, int n0, float* smem) {
  float* KKs = smem;
  float* Ews = smem + 4096;
  int tid = threadIdx.x;
  #pragma unroll
  for (int q = 0; q < 4; ++q) {
    int e4 = q * 256 + tid;
    *(float4*)&KKs[e4 * 4] = *(const float4*)(KKcc + e4 * 4);
  }
  {
    int i = tid >> 2, c4 = (tid & 3) * 4;
    *(float4*)&Ews[i * 16 + c4] = *(const float4*)(Ew + (size_t)i * DH + n0 + c4);
  }
  __syncthreads();
  #pragma unroll
  for (int q = 0; q < 4; ++q) {
    int e = q * 256 + tid;
    int mrow = e >> 4, cc = e & 15;
    float corr = 0.f;
    #pragma unroll 16
    for (int i = 0; i < 64; ++i) corr += KKs[mrow * 64 + i] * Ews[i * 16 + cc];
    float xx = H[mrow * DH + n0 + cc] - corr + b1n[n0 + cc];
    G2[mrow * DH + n0 + cc] = gelu_only(xx);
  }
}

__device__ __forceinline__ void hs_corr_job(
    const float* __restrict__ KK, const float* __restrict__ Ewj,
    float* __restrict__ dst, int bx, float* smem) {
  float* As = smem;
  float* Bs = smem + 4096;
  int tid = threadIdx.x;
  int n0 = bx * 64;
  {
    int m = tid >> 2, ib = (tid & 3) * 16;
    #pragma unroll
    for (int q = 0; q < 4; ++q) {
      float4 v = *(const float4*)(KK + m * 64 + ib + q * 4);
      As[(ib + q*4 + 0)*64 + m] = v.x;
      As[(ib + q*4 + 1)*64 + m] = v.y;
      As[(ib + q*4 + 2)*64 + m] = v.z;
      As[(ib + q*4 + 3)*64 + m] = v.w;
    }
    int kr = tid >> 4, nn = (tid & 15) * 4;
    #pragma unroll
    for (int q = 0; q < 4; ++q)
      *(float4*)&Bs[(kr + q*16)*64 + nn] = *(const float4*)(Ewj + (size_t)(kr + q*16) * DH + n0 + nn);
  }
  __syncthreads();
  int tx = tid & 15, ty = tid >> 4;
  float acc[4][4] = {{0.f}};
  #pragma unroll 16
  for (int kk = 0; kk < 64; ++kk) {
    float4 a = *(const float4*)&As[kk*64 + ty * 4];
    float4 b = *(const float4*)&Bs[kk*64 + tx * 4];
    MICRO_4x4
  }
  #pragma unroll
  for (int r = 0; r < 4; ++r) {
    float4 v = { acc[r][0], acc[r][1], acc[r][2], acc[r][3] };
    *(float4*)&dst[(ty*4 + r) * DH + n0 + tx*4] = v;
  }
}

__global__ __launch_bounds__(256) void d3_kernel(
    const float* __restrict__ KKf, int tri, int ch,
    const float* __restrict__ Ewst, const float* __restrict__ H,
    const float* __restrict__ b1n,
    float* __restrict__ G2, float* __restrict__ Hcorr) {
  __shared__ float smem[8192];
  int job = blockIdx.x;
  if (job < 32) {
    gelu2k_job(KKf + (size_t)(tri + ch) * 4096, Ewst + (size_t)ch * 32768,
               H, b1n, G2, job * 16, smem);
  } else if (ch < 7) {
    int j2 = job - 32;
    if (j2 < 8 * (ch + 1)) {
      int j = j2 >> 3, bx = j2 & 7;
      int trin = (ch + 1) * (ch + 2) / 2;
      hs_corr_job(KKf + (size_t)(trin + j) * 4096, Ewst + (size_t)j * 32768,
                  Hcorr + (size_t)j * 32768, bx, smem);
    }
  }
}

// ---------------- D4: P7 GEMM + winner (out) || hred for next chunk ----------------
__global__ __launch_bounds__(256) void d4_kernel(
    const float* __restrict__ G2, const float* __restrict__ W2n,
    float* __restrict__ Sp, const float* __restrict__ b2n,
    float* __restrict__ out, int t0, unsigned* __restrict__ cnt,
    const float* __restrict__ Hbase_n, const float* __restrict__ Hcorr, int nsl,
    const float* __restrict__ b1n,
    float* __restrict__ H, float* __restrict__ Gnext, float* __restrict__ Gp) {
  __shared__ float smem[8192];
  int b = blockIdx.x;
  int tid = threadIdx.x;
  if (b < 392) {
    int n_t = b % 49, k_t = b / 49;
    mm_nn_slice(G2, DH, W2n, DM, Sp, DM, n_t, k_t, smem);
    if (last_arrive(&cnt[n_t], 8)) {
      int n0 = n_t * 64;
      int col = n0 + (tid & 63);
      int r0 = (tid >> 6) * 16;
      float bb = b2n[col];
      for (int rr = 0; rr < 16; ++rr) {
        size_t off = (size_t)(r0 + rr) * DM + col;
        float s = 0.f;
        #pragma unroll
        for (int t = 0; t < 8; ++t) s += Sp[(size_t)t * 200704 + off];
        out[(size_t)t0 * DM + off] = s + bb;
      }
    }
  } else {
    int j = (b - 392) * 256 + tid;   // < 32768
    hred_body(j, Hbase_n, Hcorr, nsl, b1n, H, Gnext, Gp);
  }
}

extern "C" void kernel_launch(void* const* d_in, const int* in_sizes, int n_in,
                              void* d_out, int out_size, void* d_ws, size_t ws_size,
                              hipStream_t stream) {
  const float* x  = (const float*)d_in[0];
  const float* wk = (const float*)d_in[1];
  const float* bk = (const float*)d_in[2];
  const float* wv = (const float*)d_in[3];
  const float* bv = (const float*)d_in[4];
  const float* sk = (const float*)d_in[5];
  const float* sv = (const float*)d_in[6];
  const float* W1 = (const float*)d_in[7];
  const float* b1 = (const float*)d_in[8];
  const float* W2 = (const float*)d_in[9];
  const float* b2 = (const float*)d_in[10];
  float* out = (float*)d_out;
  float* ws  = (float*)d_ws;

  // counters (512 uints) then float data
  unsigned* cnt  = (unsigned*)ws;
  unsigned* c_d1 = cnt + 0;     // 49
  unsigned* c_d2 = cnt + 64;    // 8
  unsigned* c_d4 = cnt + 96;    // 49
  unsigned* c_kk = cnt + 160;   // 36
  unsigned* c_hb = cnt + 224;   // 64
  float* base  = ws + 512;
  float* nk    = base;                     // 1,605,632
  float* nv    = nk + 1605632;             // 1,605,632
  float* W2A   = nv + 1605632;             // 1,605,632
  float* W2B   = W2A + 1605632;            // 1,605,632
  float* Spart = W2B + 1605632;            // 1,605,632
  float* Hb_sl = Spart + 1605632;          // 12,845,056 (49 x 262144)
  float* KKsl  = Hb_sl + 12845056;         // 7,225,344 (36 x 49 x 4096)
  float* Hbase = KKsl + 7225344;           // 262,144
  float* KKf   = Hbase + 262144;           // 147,456
  float* Hh    = KKf + 147456;             // 32,768
  float* GA    = Hh + 32768;               // 32,768
  float* GB    = GA + 32768;               // 32,768
  float* Gp    = GB + 32768;               // 32,768
  float* Dw    = Gp + 32768;               // 200,704
  float* Ewst  = Dw + 200704;              // 262,144 (8 x 32768)
  float* Hcorr = Ewst + 262144;            // 229,376 (7 x 32768)
  float* b1ws  = Hcorr + 229376;           // 512
  float* b2ws  = b1ws + 512;               // 3,136
  float* W2buf[2] = { W2A, W2B };
  float* Gbuf[2]  = { GA, GB };

  hipMemsetAsync(cnt, 0, 2048, stream);

  // weights[i] = ETA0 * ALPHA^i * (ALPHA^63 / ALPHA^i) = ETA0 * ALPHA^63 (constant)
  float wc2 = 2.0f * (float)(0.1 * pow(0.9, 63.0));

  conv_rms<<<1568, 256, 0, stream>>>(x, wk, bk, wv, bv, sk, sv, nk, nv);
  u1_kernel<<<1764, 256, 0, stream>>>(nk, W1, KKsl, Hb_sl, KKf, Hbase, c_kk, c_hb);
  u1b_kernel<<<3136, 256, 0, stream>>>(nk, W1, Hb_sl, Hbase, c_hb);
  hred0_kernel<<<128, 256, 0, stream>>>(Hbase, b1, Hh, GA, Gp);

  for (int ch = 0; ch < 8; ++ch) {
    const float* V   = nv + (size_t)ch * 200704;
    const float* b1c = ch ? b1ws : b1;
    const float* b2c = ch ? b2ws : b2;
    const float* W2c = ch ? W2buf[(ch - 1) & 1] : W2;
    float* W2n  = W2buf[ch & 1];
    float* Gcur = Gbuf[ch & 1];
    float* Gnxt = Gbuf[(ch + 1) & 1];
    int tri = ch * (ch + 1) / 2;

    d1_kernel<<<392, 256, 0, stream>>>(Gcur, W2c, V, b2c, Spart, Dw, b2ws, c_d1, wc2);
    d2_kernel<<<784, 256, 0, stream>>>(Dw, W2c, Gcur, Spart, W2n, Gp,
                                       Ewst + (size_t)ch * 32768, b1c, b1ws, c_d2);
    d3_kernel<<<96, 256, 0, stream>>>(KKf, tri, ch, Ewst, Hh, b1ws, Gcur, Hcorr);
    d4_kernel<<<392 + (ch < 7 ? 128 : 0), 256, 0, stream>>>(
        Gcur, W2n, Spart, b2ws, out, ch * 64, c_d4,
        Hbase + (size_t)(ch + 1) * 32768, Hcorr, ch + 1, b1ws, Hh, Gnxt, Gp);
  }
}

// Round 10
// 649.714 us; speedup vs baseline: 2.0638x; 2.0638x over previous
//
#include <hip/hip_runtime.h>
#include <math.h>

#define DM 3136
#define DH 512

#define MICRO_4x4 \
    acc[0][0] += a.x*b.x; acc[0][1] += a.x*b.y; acc[0][2] += a.x*b.z; acc[0][3] += a.x*b.w; \
    acc[1][0] += a.y*b.x; acc[1][1] += a.y*b.y; acc[1][2] += a.y*b.z; acc[1][3] += a.y*b.w; \
    acc[2][0] += a.z*b.x; acc[2][1] += a.z*b.y; acc[2][2] += a.z*b.z; acc[2][3] += a.z*b.w; \
    acc[3][0] += a.w*b.x; acc[3][1] += a.w*b.y; acc[3][2] += a.w*b.z; acc[3][3] += a.w*b.w;

// ---- stage a 64x64 tile (row stride ld) into contiguous LDS [64][64] ----
// Uses direct global->LDS DMA where available (dest is wave-uniform base + lane*16).
__device__ __forceinline__ void stage_dma_tile(const float* __restrict__ src, int ld,
                                               float* __restrict__ dst) {
#if __has_builtin(__builtin_amdgcn_global_load_lds)
  int w = threadIdx.x >> 6;          // wave id (4 waves)
  int lane = threadIdx.x & 63;
  int lr = lane >> 4, lc = (lane & 15) * 4;
  #pragma unroll
  for (int q = 0; q < 4; ++q) {
    int rb = w * 4 + q * 16;         // wave-uniform row block (4 rows = 1KB)
    const float* g = src + (size_t)(rb + lr) * ld + lc;
    __builtin_amdgcn_global_load_lds(
        (const __attribute__((address_space(1))) void*)g,
        (__attribute__((address_space(3))) void*)(dst + rb * 64), 16, 0, 0);
  }
#else
  int r = threadIdx.x >> 4;
  int c = (threadIdx.x & 15) * 4;
  #pragma unroll
  for (int q = 0; q < 4; ++q)
    *(float4*)&dst[(r + q*16)*64 + c] = *(const float4*)(src + (size_t)(r + q*16) * ld + c);
#endif
}

// ---------------- gelu ----------------
__device__ __forceinline__ void gelu_both(float xx, float& g, float& gp) {
  const float c = 0.7978845608028654f;
  const float a = 0.044715f;
  float x2 = xx * xx;
  float u = c * (xx + a * xx * x2);
  float t = tanhf(u);
  g  = 0.5f * xx * (1.f + t);
  gp = 0.5f * (1.f + t) + 0.5f * xx * (1.f - t * t) * c * (1.f + 3.f * a * x2);
}
__device__ __forceinline__ float gelu_only(float xx) {
  const float c = 0.7978845608028654f;
  const float a = 0.044715f;
  float u = c * (xx + a * xx * xx * xx);
  return 0.5f * xx * (1.f + tanhf(u));
}

// ---------------- conv3x3 + RMSNorm (proven R2) ----------------
__global__ __launch_bounds__(256) void conv_rms(
    const float* __restrict__ x,
    const float* __restrict__ wk, const float* __restrict__ bk,
    const float* __restrict__ wv, const float* __restrict__ bv,
    const float* __restrict__ sk, const float* __restrict__ sv,
    float* __restrict__ nk, float* __restrict__ nv) {
  __shared__ float swk[144], swv[144], sb[16];
  int tid = threadIdx.x;
  if (tid < 144) { swk[tid] = wk[tid]; swv[tid] = wv[tid]; }
  if (tid < 4) {
    sb[tid] = bk[tid]; sb[4 + tid] = bv[tid];
    sb[8 + tid] = sk[tid]; sb[12 + tid] = sv[tid];
  }
  __syncthreads();
  int idx = blockIdx.x * 256 + tid;
  int t = idx / 784, hw = idx - t * 784;
  int h = hw / 28, w = hw - h * 28;
  float ak[4], av[4];
  #pragma unroll
  for (int c = 0; c < 4; ++c) { ak[c] = sb[c]; av[c] = sb[4 + c]; }
  const float* xt = x + (size_t)t * DM;
  for (int kh = 0; kh < 3; ++kh) {
    int ih = h + kh - 1;
    if (ih < 0 || ih >= 28) continue;
    for (int kw = 0; kw < 3; ++kw) {
      int iw = w + kw - 1;
      if (iw < 0 || iw >= 28) continue;
      int base = (kh * 3 + kw) * 16;
      #pragma unroll
      for (int ci = 0; ci < 4; ++ci) {
        float xv = xt[ci * 784 + ih * 28 + iw];
        #pragma unroll
        for (int co = 0; co < 4; ++co) {
          ak[co] += xv * swk[base + ci * 4 + co];
          av[co] += xv * swv[base + ci * 4 + co];
        }
      }
    }
  }
  float mk = (ak[0]*ak[0] + ak[1]*ak[1] + ak[2]*ak[2] + ak[3]*ak[3]) * 0.25f + 1e-6f;
  float mv = (av[0]*av[0] + av[1]*av[1] + av[2]*av[2] + av[3]*av[3]) * 0.25f + 1e-6f;
  float ik = 1.f / sqrtf(mk), iv = 1.f / sqrtf(mv);
  float4 ok = { ak[0]*ik*sb[8],  ak[1]*ik*sb[9],  ak[2]*ik*sb[10], ak[3]*ik*sb[11] };
  float4 ov = { av[0]*iv*sb[12], av[1]*iv*sb[13], av[2]*iv*sb[14], av[3]*iv*sb[15] };
  *(float4*)&nk[(size_t)idx * 4] = ok;
  *(float4*)&nv[(size_t)idx * 4] = ov;
}

// ---------------- mm_nn body: A[64,K]@B tile, DMA B-staging ----------------
__device__ __forceinline__ void mm_nn_body(
    const float* __restrict__ A, int lda, const float* __restrict__ B, int ldb,
    float* __restrict__ Cp, int ldc, int n_t, int k_t, float* smem) {
  float* As = smem;          // [k][m]
  float* Bs = smem + 4096;   // [k][n]
  int tid = threadIdx.x;
  int n0 = n_t * 64, k0 = k_t * 64;
  stage_dma_tile(B + (size_t)k0 * ldb + n0, ldb, Bs);   // async DMA
  {
    int m  = tid >> 2;
    int kb = (tid & 3) * 16;
    const float* Ap = A + (size_t)m * lda + k0 + kb;
    #pragma unroll
    for (int q = 0; q < 4; ++q) {
      float4 v = *(const float4*)(Ap + q * 4);
      As[(kb + q*4 + 0)*64 + m] = v.x;
      As[(kb + q*4 + 1)*64 + m] = v.y;
      As[(kb + q*4 + 2)*64 + m] = v.z;
      As[(kb + q*4 + 3)*64 + m] = v.w;
    }
  }
  __syncthreads();
  int tx = tid & 15, ty = tid >> 4;
  float acc[4][4] = {{0.f}};
  #pragma unroll 16
  for (int kk = 0; kk < 64; ++kk) {
    float4 a = *(const float4*)&As[kk*64 + ty * 4];
    float4 b = *(const float4*)&Bs[kk*64 + tx * 4];
    MICRO_4x4
  }
  float* Cb = Cp + (size_t)k_t * 64 * ldc + n0 + tx * 4;
  #pragma unroll
  for (int r = 0; r < 4; ++r) {
    float4 v = { acc[r][0], acc[r][1], acc[r][2], acc[r][3] };
    *(float4*)&Cb[(size_t)(ty * 4 + r) * ldc] = v;
  }
}

// ---------------- mm_nt body: A[64,K]@B^T (B [N,K] rows) — proven R7 ----------------
__device__ __forceinline__ void mm_nt_body(
    const float* __restrict__ A, int lda, const float* __restrict__ B, int ldb,
    float* __restrict__ Cp, int ldc, int n_t, int k_t, float* smem) {
  float* As = smem;
  float* Bs = smem + 4096;
  int tid = threadIdx.x;
  int n0 = n_t * 64, k0 = k_t * 64;
  {
    int m  = tid >> 2;
    int kb = (tid & 3) * 16;
    const float* Ap = A + (size_t)m * lda + k0 + kb;
    const float* Bp = B + (size_t)(n0 + m) * ldb + k0 + kb;
    #pragma unroll
    for (int q = 0; q < 4; ++q) {
      float4 va = *(const float4*)(Ap + q * 4);
      As[(kb + q*4 + 0)*64 + m] = va.x;
      As[(kb + q*4 + 1)*64 + m] = va.y;
      As[(kb + q*4 + 2)*64 + m] = va.z;
      As[(kb + q*4 + 3)*64 + m] = va.w;
      float4 vb = *(const float4*)(Bp + q * 4);
      Bs[(kb + q*4 + 0)*64 + m] = vb.x;
      Bs[(kb + q*4 + 1)*64 + m] = vb.y;
      Bs[(kb + q*4 + 2)*64 + m] = vb.z;
      Bs[(kb + q*4 + 3)*64 + m] = vb.w;
    }
  }
  __syncthreads();
  int tx = tid & 15, ty = tid >> 4;
  float acc[4][4] = {{0.f}};
  #pragma unroll 16
  for (int kk = 0; kk < 64; ++kk) {
    float4 a = *(const float4*)&As[kk*64 + ty * 4];
    float4 b = *(const float4*)&Bs[kk*64 + tx * 4];
    MICRO_4x4
  }
  float* Cb = Cp + (size_t)k_t * 64 * ldc + n0 + tx * 4;
  #pragma unroll
  for (int r = 0; r < 4; ++r) {
    float4 v = { acc[r][0], acc[r][1], acc[r][2], acc[r][3] };
    *(float4*)&Cb[(size_t)(ty * 4 + r) * ldc] = v;
  }
}

// ---------------- upd64: Cnew = Cold - A^T B  (DMA both operands) ----------------
__device__ __forceinline__ void upd64_dev(
    const float* __restrict__ A, int P,
    const float* __restrict__ B, int Q,
    const float* __restrict__ Cold, float* __restrict__ Cnew,
    int bx, int by, float* smem) {
  float* As = smem;          // [i][p]
  float* Bs = smem + 4096;   // [i][q]
  int q0 = bx * 64;
  int p0 = by * 64;
  stage_dma_tile(A + p0, P, As);
  stage_dma_tile(B + q0, Q, Bs);
  __syncthreads();
  int tid = threadIdx.x;
  int tx = tid & 15, ty = tid >> 4;
  float acc[4][4] = {{0.f}};
  #pragma unroll 16
  for (int i = 0; i < 64; ++i) {
    float4 a = *(const float4*)&As[i*64 + ty * 4];
    float4 b = *(const float4*)&Bs[i*64 + tx * 4];
    MICRO_4x4
  }
  #pragma unroll
  for (int r = 0; r < 4; ++r) {
    size_t off = (size_t)(p0 + ty*4 + r) * Q + q0 + tx*4;
    float4 co = *(const float4*)&Cold[off];
    float4 v = { co.x - acc[r][0], co.y - acc[r][1], co.z - acc[r][2], co.w - acc[r][3] };
    *(float4*)&Cnew[off] = v;
  }
}

// ---------------- kk_slice: one 64-k slice of K_c K_j^T (proven R7) ----------------
__device__ __forceinline__ void kk_slice(int p, int s, const float* __restrict__ nk,
                                         float* __restrict__ KKsl, float* smem) {
  float* As = smem;
  float* Bs = smem + 4096;
  int tid = threadIdx.x;
  int c = 0;
  while ((c + 1) * (c + 2) / 2 <= p) ++c;
  int j = p - c * (c + 1) / 2;
  const float* A = nk + (size_t)c * 64 * DM;
  const float* B = nk + (size_t)j * 64 * DM;
  int k0 = s * 64;
  {
    int m  = tid >> 2;
    int kb = (tid & 3) * 16;
    const float* Ap = A + (size_t)m * DM + k0 + kb;
    const float* Bp = B + (size_t)m * DM + k0 + kb;
    #pragma unroll
    for (int q = 0; q < 4; ++q) {
      float4 va = *(const float4*)(Ap + q * 4);
      As[(kb + q*4 + 0)*64 + m] = va.x;
      As[(kb + q*4 + 1)*64 + m] = va.y;
      As[(kb + q*4 + 2)*64 + m] = va.z;
      As[(kb + q*4 + 3)*64 + m] = va.w;
      float4 vb = *(const float4*)(Bp + q * 4);
      Bs[(kb + q*4 + 0)*64 + m] = vb.x;
      Bs[(kb + q*4 + 1)*64 + m] = vb.y;
      Bs[(kb + q*4 + 2)*64 + m] = vb.z;
      Bs[(kb + q*4 + 3)*64 + m] = vb.w;
    }
  }
  __syncthreads();
  int tx = tid & 15, ty = tid >> 4;
  float acc[4][4] = {{0.f}};
  #pragma unroll 16
  for (int kk = 0; kk < 64; ++kk) {
    float4 a = *(const float4*)&As[kk*64 + ty * 4];
    float4 b = *(const float4*)&Bs[kk*64 + tx * 4];
    MICRO_4x4
  }
  float* dst = KKsl + ((size_t)p * 49 + s) * 4096;
  #pragma unroll
  for (int r = 0; r < 4; ++r) {
    float4 v = { acc[r][0], acc[r][1], acc[r][2], acc[r][3] };
    *(float4*)&dst[(ty*4 + r) * 64 + tx*4] = v;
  }
}

// ---------------- hb_long: 7-round Hbase block with VGPR prefetch pipelining ----------------
__device__ __forceinline__ void hb_long(int jb, const float* __restrict__ K,
                                        const float* __restrict__ W1,
                                        float* __restrict__ Hb_sl, float* smem) {
  float* As = smem;
  float* Bs = smem + 4096;
  int tid = threadIdx.x;
  int s  = jb % 7;
  int nt = (jb / 7) & 7;
  int mt = jb / 56;
  int n0 = nt * 64, m0 = mt * 64;
  int m = tid >> 2, kb = (tid & 3) * 16;
  int kr = tid >> 4, nn = (tid & 15) * 4;
  int tx = tid & 15, ty = tid >> 4;
  float acc[4][4] = {{0.f}};
  int k0 = s * 448;
  const float* Ap = K + (size_t)(m0 + m) * DM + k0 + kb;
  const float* Bp = W1 + (size_t)(k0 + kr) * DH + n0 + nn;
  float4 pa[4], pb[4];
  #pragma unroll
  for (int q = 0; q < 4; ++q) {
    pa[q] = *(const float4*)(Ap + q * 4);
    pb[q] = *(const float4*)(Bp + (size_t)q * 16 * DH);
  }
  for (int it = 0; it < 7; ++it) {
    __syncthreads();
    #pragma unroll
    for (int q = 0; q < 4; ++q) {
      As[(kb + q*4 + 0)*64 + m] = pa[q].x;
      As[(kb + q*4 + 1)*64 + m] = pa[q].y;
      As[(kb + q*4 + 2)*64 + m] = pa[q].z;
      As[(kb + q*4 + 3)*64 + m] = pa[q].w;
      *(float4*)&Bs[(kr + q*16)*64 + nn] = pb[q];
    }
    __syncthreads();
    if (it < 6) {
      const float* Ap2 = Ap + (it + 1) * 64;
      const float* Bp2 = Bp + (size_t)(it + 1) * 64 * DH;
      #pragma unroll
      for (int q = 0; q < 4; ++q) {
        pa[q] = *(const float4*)(Ap2 + q * 4);
        pb[q] = *(const float4*)(Bp2 + (size_t)q * 16 * DH);
      }
    }
    #pragma unroll 16
    for (int kk = 0; kk < 64; ++kk) {
      float4 a = *(const float4*)&As[kk*64 + ty * 4];
      float4 b = *(const float4*)&Bs[kk*64 + tx * 4];
      MICRO_4x4
    }
  }
  float* dst = Hb_sl + (size_t)s * 262144;
  #pragma unroll
  for (int r = 0; r < 4; ++r) {
    float4 v = { acc[r][0], acc[r][1], acc[r][2], acc[r][3] };
    *(float4*)&dst[(size_t)(m0 + ty*4 + r) * 512 + n0 + tx*4] = v;
  }
}

// u1: KK slices (1764) + Hbase long blocks (448)
__global__ __launch_bounds__(256) void u1_kernel(
    const float* __restrict__ nk, const float* __restrict__ W1,
    float* __restrict__ KKsl, float* __restrict__ Hb_sl) {
  __shared__ float smem[8192];
  int job = blockIdx.x;
  if (job < 1764) kk_slice(job / 49, job % 49, nk, KKsl, smem);
  else            hb_long(job - 1764, nk, W1, Hb_sl, smem);
}

// u2: KKf (sum 49) + Hbase (sum 7)
__global__ __launch_bounds__(256) void u2_kernel(
    const float* __restrict__ KKsl, const float* __restrict__ Hb_sl,
    float* __restrict__ KKf, float* __restrict__ Hbase) {
  int i = blockIdx.x * 256 + threadIdx.x;
  if (i < 147456) {
    int pair = i >> 12, e = i & 4095;
    float s = 0.f;
    for (int t = 0; t < 49; ++t) s += KKsl[((size_t)pair * 49 + t) * 4096 + e];
    KKf[i] = s;
  } else {
    int j = i - 147456;   // < 262144
    float s = 0.f;
    #pragma unroll
    for (int t = 0; t < 7; ++t) s += Hb_sl[(size_t)t * 262144 + j];
    Hbase[j] = s;
  }
}

// ---------------- hred body + hred0 ----------------
__device__ __forceinline__ void hred_body(
    int j, const float* __restrict__ Hb_c, const float* __restrict__ Hcorr, int nsl,
    const float* __restrict__ b1v,
    float* __restrict__ H, float* __restrict__ G, float* __restrict__ Gp) {
  float s = Hb_c[j];
  for (int t = 0; t < nsl; ++t) s -= Hcorr[(size_t)t * 32768 + j];
  H[j] = s;
  float g, gp;
  gelu_both(s + b1v[j & 511], g, gp);
  G[j] = g; Gp[j] = gp;
}

__global__ __launch_bounds__(256) void hred0_kernel(
    const float* __restrict__ Hbase, const float* __restrict__ b1,
    float* __restrict__ H, float* __restrict__ G, float* __restrict__ Gp) {
  int j = blockIdx.x * 256 + threadIdx.x;
  hred_body(j, Hbase, (const float*)nullptr, 0, b1, H, G, Gp);
}

// ---------------- hs_corr job (DMA Ew staging) ----------------
__device__ __forceinline__ void hs_corr_job(
    const float* __restrict__ KK, const float* __restrict__ Ewj,
    float* __restrict__ dst, int bx, float* smem) {
  float* As = smem;
  float* Bs = smem + 4096;
  int tid = threadIdx.x;
  int n0 = bx * 64;
  stage_dma_tile(Ewj + n0, DH, Bs);
  {
    int m = tid >> 2, ib = (tid & 3) * 16;
    #pragma unroll
    for (int q = 0; q < 4; ++q) {
      float4 v = *(const float4*)(KK + m * 64 + ib + q * 4);
      As[(ib + q*4 + 0)*64 + m] = v.x;
      As[(ib + q*4 + 1)*64 + m] = v.y;
      As[(ib + q*4 + 2)*64 + m] = v.z;
      As[(ib + q*4 + 3)*64 + m] = v.w;
    }
  }
  __syncthreads();
  int tx = tid & 15, ty = tid >> 4;
  float acc[4][4] = {{0.f}};
  #pragma unroll 16
  for (int kk = 0; kk < 64; ++kk) {
    float4 a = *(const float4*)&As[kk*64 + ty * 4];
    float4 b = *(const float4*)&Bs[kk*64 + tx * 4];
    MICRO_4x4
  }
  #pragma unroll
  for (int r = 0; r < 4; ++r) {
    float4 v = { acc[r][0], acc[r][1], acc[r][2], acc[r][3] };
    *(float4*)&dst[(ty*4 + r) * DH + n0 + tx*4] = v;
  }
}

// ---------------- gelu2k job (proven R7) ----------------
__device__ __forceinline__ void gelu2k_job(
    const float* __restrict__ KKcc, const float* __restrict__ Ew,
    const float* __restrict__ H, const float* __restrict__ b1n,
    float* __restrict__ G2, int n0, float* smem) {
  float* KKs = smem;
  float* Ews = smem + 4096;
  int tid = threadIdx.x;
  #pragma unroll
  for (int q = 0; q < 4; ++q) {
    int e4 = q * 256 + tid;
    *(float4*)&KKs[e4 * 4] = *(const float4*)(KKcc + e4 * 4);
  }
  {
    int i = tid >> 2, c4 = (tid & 3) * 4;
    *(float4*)&Ews[i * 16 + c4] = *(const float4*)(Ew + (size_t)i * DH + n0 + c4);
  }
  __syncthreads();
  #pragma unroll
  for (int q = 0; q < 4; ++q) {
    int e = q * 256 + tid;
    int mrow = e >> 4, cc = e & 15;
    float corr = 0.f;
    #pragma unroll 16
    for (int i = 0; i < 64; ++i) corr += KKs[mrow * 64 + i] * Ews[i * 16 + cc];
    float xx = H[mrow * DH + n0 + cc] - corr + b1n[n0 + cc];
    G2[mrow * DH + n0 + cc] = gelu_only(xx);
  }
}

// ---------------- per-chunk dispatch kernels ----------------
// P3 (392) || Hcorr for chunk ch+1, j<ch (8*ch)
__global__ __launch_bounds__(256) void p3h_kernel(
    const float* __restrict__ G, const float* __restrict__ W2c,
    float* __restrict__ Sp,
    const float* __restrict__ KKf, int ch,
    const float* __restrict__ Ewst, float* __restrict__ Hcorr) {
  __shared__ float smem[8192];
  int b = blockIdx.x;
  if (b < 392) {
    mm_nn_body(G, DH, W2c, DM, Sp, DM, b % 49, b / 49, smem);
  } else {
    int j2 = b - 392;
    int j = j2 >> 3, bx = j2 & 7;      // j < ch guaranteed by grid
    int trin = (ch + 1) * (ch + 2) / 2;
    hs_corr_job(KKf + (size_t)(trin + j) * 4096, Ewst + (size_t)j * 32768,
                Hcorr + (size_t)j * 32768, bx, smem);
  }
}

// red_Db2 (49) — proven R7
__global__ __launch_bounds__(256) void red_Db2(
    const float* __restrict__ Dp, const float* __restrict__ b2c,
    const float* __restrict__ V, float wc2,
    float* __restrict__ Dw, float* __restrict__ b2n) {
  __shared__ float sm[256];
  int tid = threadIdx.x;
  int col = blockIdx.x * 64 + (tid & 63);
  int r0 = (tid >> 6) * 16;
  float bb = b2c[col];
  float cs = 0.f;
  for (int rr = 0; rr < 16; ++rr) {
    size_t off = (size_t)(r0 + rr) * DM + col;
    float s = 0.f;
    #pragma unroll
    for (int t = 0; t < 8; ++t) s += Dp[(size_t)t * 200704 + off];
    float d = wc2 * (s + bb - V[off]);
    Dw[off] = d;
    cs += d;
  }
  sm[tid] = cs;
  __syncthreads();
  if (tid < 64) {
    float tot = sm[tid] + sm[tid + 64] + sm[tid + 128] + sm[tid + 192];
    b2n[blockIdx.x * 64 + tid] = b2c[blockIdx.x * 64 + tid] - tot;
  }
}

// P4 (392) || W2 update (392)  — needs W2 ping-pong
__global__ __launch_bounds__(256) void p4w2_kernel(
    const float* __restrict__ Dw, const float* __restrict__ W2c,
    const float* __restrict__ G, float* __restrict__ Sp,
    float* __restrict__ W2n) {
  __shared__ float smem[8192];
  int b = blockIdx.x;
  if (b < 392) mm_nt_body(Dw, DM, W2c, DM, Sp, DH, b & 7, b >> 3, smem);
  else {
    int li = b - 392;
    upd64_dev(G, DH, Dw, DM, W2c, W2n, li % 49, li / 49, smem);
  }
}

// Ew + b1 update (128) — comb5 else-branch, standalone
__global__ __launch_bounds__(256) void ewb1_kernel(
    const float* __restrict__ Esl, const float* __restrict__ Gp,
    float* __restrict__ Ew, const float* __restrict__ b1old, float* __restrict__ b1new) {
  __shared__ float smem[256];
  int tid = threadIdx.x;
  int n0 = blockIdx.x * 4;
  int row = tid >> 2, c = tid & 3;
  int col = n0 + c;
  float s = 0.f;
  #pragma unroll
  for (int sl = 0; sl < 49; ++sl) s += Esl[(size_t)sl * 32768 + row * 512 + col];
  float ew = s * Gp[row * 512 + col];
  Ew[row * 512 + col] = ew;
  smem[tid] = ew;
  __syncthreads();
  for (int off = 128; off >= 4; off >>= 1) {
    if (tid < off) smem[tid] += smem[tid + off];
    __syncthreads();
  }
  if (tid < 4) b1new[n0 + tid] = b1old[n0 + tid] - smem[tid];
}

// gelu2k (32) || Hcorr j=ch (8, if ch<7)
__global__ __launch_bounds__(256) void g2s_kernel(
    const float* __restrict__ KKf, int tri, int ch,
    const float* __restrict__ Ewst, const float* __restrict__ H,
    const float* __restrict__ b1n,
    float* __restrict__ G2, float* __restrict__ Hcorr) {
  __shared__ float smem[8192];
  int b = blockIdx.x;
  if (b < 32) {
    gelu2k_job(KKf + (size_t)(tri + ch) * 4096, Ewst + (size_t)ch * 32768,
               H, b1n, G2, b * 16, smem);
  } else {
    int bx = b - 32;
    int trin = (ch + 1) * (ch + 2) / 2;
    hs_corr_job(KKf + (size_t)(trin + ch) * 4096, Ewst + (size_t)ch * 32768,
                Hcorr + (size_t)ch * 32768, bx, smem);
  }
}

// P7 (392)
__global__ __launch_bounds__(256) void p7_kernel(
    const float* __restrict__ G2, const float* __restrict__ W2n,
    float* __restrict__ Sp) {
  __shared__ float smem[8192];
  mm_nn_body(G2, DH, W2n, DM, Sp, DM, blockIdx.x % 49, blockIdx.x / 49, smem);
}

// out rows (784) || hred for next chunk (128) — proven R7
__global__ __launch_bounds__(256) void redy_hg(
    const float* __restrict__ Sp, const float* __restrict__ b2n,
    float* __restrict__ out, int t0,
    int do_hg, const float* __restrict__ Hbase_n, const float* __restrict__ Hcorr,
    int nsl, const float* __restrict__ b1n,
    float* __restrict__ H, float* __restrict__ G, float* __restrict__ Gp) {
  int job = blockIdx.x, tid = threadIdx.x;
  if (job < 784) {
    int j = job * 256 + tid;
    float s = 0.f;
    #pragma unroll
    for (int t = 0; t < 8; ++t) s += Sp[(size_t)t * 200704 + j];
    int i = j / DM;
    int d = j - i * DM;
    out[(size_t)t0 * DM + j] = s + b2n[d];
  } else if (do_hg) {
    int j = (job - 784) * 256 + tid;   // < 32768
    hred_body(j, Hbase_n, Hcorr, nsl, b1n, H, G, Gp);
  }
}

extern "C" void kernel_launch(void* const* d_in, const int* in_sizes, int n_in,
                              void* d_out, int out_size, void* d_ws, size_t ws_size,
                              hipStream_t stream) {
  const float* x  = (const float*)d_in[0];
  const float* wk = (const float*)d_in[1];
  const float* bk = (const float*)d_in[2];
  const float* wv = (const float*)d_in[3];
  const float* bv = (const float*)d_in[4];
  const float* sk = (const float*)d_in[5];
  const float* sv = (const float*)d_in[6];
  const float* W1 = (const float*)d_in[7];
  const float* b1 = (const float*)d_in[8];
  const float* W2 = (const float*)d_in[9];
  const float* b2 = (const float*)d_in[10];
  float* out = (float*)d_out;
  float* ws  = (float*)d_ws;

  // workspace layout (floats)
  float* nk    = ws;                       // 1,605,632
  float* nv    = nk + 1605632;             // 1,605,632
  float* W2A   = nv + 1605632;             // 1,605,632
  float* W2B   = W2A + 1605632;            // 1,605,632
  float* Spart = W2B + 1605632;            // 1,605,632
  float* Hb_sl = Spart + 1605632;          // 1,835,008 (7 x 262144)
  float* KKsl  = Hb_sl + 1835008;          // 7,225,344 (36 x 49 x 4096)
  float* Hbase = KKsl + 7225344;           // 262,144
  float* KKf   = Hbase + 262144;           // 147,456
  float* Hh    = KKf + 147456;             // 32,768
  float* G     = Hh + 32768;               // 32,768
  float* Gp    = G + 32768;                // 32,768
  float* Dw    = Gp + 32768;               // 200,704
  float* Ewst  = Dw + 200704;              // 262,144 (8 x 32768)
  float* Hcorr = Ewst + 262144;            // 229,376 (7 x 32768)
  float* b1ws  = Hcorr + 229376;           // 512
  float* b2ws  = b1ws + 512;               // 3,136
  float* W2buf[2] = { W2A, W2B };

  // weights[i] = ETA0 * ALPHA^i * (ALPHA^63 / ALPHA^i) = ETA0 * ALPHA^63 (constant)
  float wc2 = 2.0f * (float)(0.1 * pow(0.9, 63.0));

  conv_rms<<<1568, 256, 0, stream>>>(x, wk, bk, wv, bv, sk, sv, nk, nv);
  u1_kernel<<<2212, 256, 0, stream>>>(nk, W1, KKsl, Hb_sl);
  u2_kernel<<<1600, 256, 0, stream>>>(KKsl, Hb_sl, KKf, Hbase);
  hred0_kernel<<<128, 256, 0, stream>>>(Hbase, b1, Hh, G, Gp);

  for (int ch = 0; ch < 8; ++ch) {
    const float* V   = nv + (size_t)ch * 200704;
    const float* b1c = ch ? b1ws : b1;
    const float* b2c = ch ? b2ws : b2;
    const float* W2c = ch ? W2buf[(ch - 1) & 1] : W2;
    float* W2n = W2buf[ch & 1];
    float* Ewc = Ewst + (size_t)ch * 32768;
    int tri = ch * (ch + 1) / 2;

    // P3: pred slices = G @ W2c  || Hcorr (chunk ch+1, j<ch)
    p3h_kernel<<<392 + (ch < 7 ? 8 * ch : 0), 256, 0, stream>>>(
        G, W2c, Spart, KKf, ch, Ewst, Hcorr);
    // Dw = wc2*(pred + b2 - V); b2ws update
    red_Db2<<<49, 256, 0, stream>>>(Spart, b2c, V, wc2, Dw, b2ws);
    // P4: E slices = Dw @ W2c^T  ||  W2n = W2c - G^T Dw
    p4w2_kernel<<<784, 256, 0, stream>>>(Dw, W2c, G, Spart, W2n);
    // Ew = redE * Gp; b1ws update
    ewb1_kernel<<<128, 256, 0, stream>>>(Spart, Gp, Ewc, b1c, b1ws);
    // G2 = gelu(H - KK[c,c]@Ew + b1ws)  ||  Hcorr j=ch for chunk ch+1
    g2s_kernel<<<32 + (ch < 7 ? 8 : 0), 256, 0, stream>>>(
        KKf, tri, ch, Ewst, Hh, b1ws, G, Hcorr);
    // P7: Y slices = G2 @ W2n
    p7_kernel<<<392, 256, 0, stream>>>(G, W2n, Spart);
    // out rows  ||  H/G/Gp for chunk ch+1
    redy_hg<<<784 + (ch < 7 ? 128 : 0), 256, 0, stream>>>(
        Spart, b2ws, out, ch * 64, ch < 7 ? 1 : 0,
        Hbase + (size_t)(ch + 1) * 32768, Hcorr, ch + 1, b1ws, Hh, G, Gp);
  }
}

// Round 11
// 603.362 us; speedup vs baseline: 2.2224x; 1.0768x over previous
//
#include <hip/hip_runtime.h>
#include <math.h>

#define DM 3136
#define DH 512

#define MICRO_4x4 \
    acc[0][0] += a.x*b.x; acc[0][1] += a.x*b.y; acc[0][2] += a.x*b.z; acc[0][3] += a.x*b.w; \
    acc[1][0] += a.y*b.x; acc[1][1] += a.y*b.y; acc[1][2] += a.y*b.z; acc[1][3] += a.y*b.w; \
    acc[2][0] += a.z*b.x; acc[2][1] += a.z*b.y; acc[2][2] += a.z*b.z; acc[2][3] += a.z*b.w; \
    acc[3][0] += a.w*b.x; acc[3][1] += a.w*b.y; acc[3][2] += a.w*b.z; acc[3][3] += a.w*b.w;

// ---------------- gelu ----------------
__device__ __forceinline__ void gelu_both(float xx, float& g, float& gp) {
  const float c = 0.7978845608028654f;
  const float a = 0.044715f;
  float x2 = xx * xx;
  float u = c * (xx + a * xx * x2);
  float t = tanhf(u);
  g  = 0.5f * xx * (1.f + t);
  gp = 0.5f * (1.f + t) + 0.5f * xx * (1.f - t * t) * c * (1.f + 3.f * a * x2);
}
__device__ __forceinline__ float gelu_only(float xx) {
  const float c = 0.7978845608028654f;
  const float a = 0.044715f;
  float u = c * (xx + a * xx * xx * xx);
  return 0.5f * xx * (1.f + tanhf(u));
}

// ---------------- conv3x3 + RMSNorm (proven R2) ----------------
__global__ __launch_bounds__(256) void conv_rms(
    const float* __restrict__ x,
    const float* __restrict__ wk, const float* __restrict__ bk,
    const float* __restrict__ wv, const float* __restrict__ bv,
    const float* __restrict__ sk, const float* __restrict__ sv,
    float* __restrict__ nk, float* __restrict__ nv) {
  __shared__ float swk[144], swv[144], sb[16];
  int tid = threadIdx.x;
  if (tid < 144) { swk[tid] = wk[tid]; swv[tid] = wv[tid]; }
  if (tid < 4) {
    sb[tid] = bk[tid]; sb[4 + tid] = bv[tid];
    sb[8 + tid] = sk[tid]; sb[12 + tid] = sv[tid];
  }
  __syncthreads();
  int idx = blockIdx.x * 256 + tid;
  int t = idx / 784, hw = idx - t * 784;
  int h = hw / 28, w = hw - h * 28;
  float ak[4], av[4];
  #pragma unroll
  for (int c = 0; c < 4; ++c) { ak[c] = sb[c]; av[c] = sb[4 + c]; }
  const float* xt = x + (size_t)t * DM;
  for (int kh = 0; kh < 3; ++kh) {
    int ih = h + kh - 1;
    if (ih < 0 || ih >= 28) continue;
    for (int kw = 0; kw < 3; ++kw) {
      int iw = w + kw - 1;
      if (iw < 0 || iw >= 28) continue;
      int base = (kh * 3 + kw) * 16;
      #pragma unroll
      for (int ci = 0; ci < 4; ++ci) {
        float xv = xt[ci * 784 + ih * 28 + iw];
        #pragma unroll
        for (int co = 0; co < 4; ++co) {
          ak[co] += xv * swk[base + ci * 4 + co];
          av[co] += xv * swv[base + ci * 4 + co];
        }
      }
    }
  }
  float mk = (ak[0]*ak[0] + ak[1]*ak[1] + ak[2]*ak[2] + ak[3]*ak[3]) * 0.25f + 1e-6f;
  float mv = (av[0]*av[0] + av[1]*av[1] + av[2]*av[2] + av[3]*av[3]) * 0.25f + 1e-6f;
  float ik = 1.f / sqrtf(mk), iv = 1.f / sqrtf(mv);
  float4 ok = { ak[0]*ik*sb[8],  ak[1]*ik*sb[9],  ak[2]*ik*sb[10], ak[3]*ik*sb[11] };
  float4 ov = { av[0]*iv*sb[12], av[1]*iv*sb[13], av[2]*iv*sb[14], av[3]*iv*sb[15] };
  *(float4*)&nk[(size_t)idx * 4] = ok;
  *(float4*)&nv[(size_t)idx * 4] = ov;
}

// ---------------- mm_nn: A[64,K]@B tile -> slice (proven R7) ----------------
__device__ __forceinline__ void mm_nn_slice(
    const float* __restrict__ A, int lda, const float* __restrict__ B, int ldb,
    float* __restrict__ Cp, int ldc, int n_t, int k_t, float* smem) {
  float* As = smem;
  float* Bs = smem + 4096;
  int tid = threadIdx.x;
  int n0 = n_t * 64, k0 = k_t * 64;
  {
    int m  = tid >> 2;
    int kb = (tid & 3) * 16;
    const float* Ap = A + (size_t)m * lda + k0 + kb;
    #pragma unroll
    for (int q = 0; q < 4; ++q) {
      float4 v = *(const float4*)(Ap + q * 4);
      As[(kb + q*4 + 0)*64 + m] = v.x;
      As[(kb + q*4 + 1)*64 + m] = v.y;
      As[(kb + q*4 + 2)*64 + m] = v.z;
      As[(kb + q*4 + 3)*64 + m] = v.w;
    }
    int kr = tid >> 4;
    int nn = (tid & 15) * 4;
    #pragma unroll
    for (int q = 0; q < 4; ++q)
      *(float4*)&Bs[(kr + q*16)*64 + nn] = *(const float4*)(B + (size_t)(k0 + kr + q*16) * ldb + n0 + nn);
  }
  __syncthreads();
  int tx = tid & 15, ty = tid >> 4;
  float acc[4][4] = {{0.f}};
  #pragma unroll 16
  for (int kk = 0; kk < 64; ++kk) {
    float4 a = *(const float4*)&As[kk*64 + ty * 4];
    float4 b = *(const float4*)&Bs[kk*64 + tx * 4];
    MICRO_4x4
  }
  float* Cb = Cp + (size_t)k_t * 64 * ldc + n0 + tx * 4;
  #pragma unroll
  for (int r = 0; r < 4; ++r) {
    float4 v = { acc[r][0], acc[r][1], acc[r][2], acc[r][3] };
    *(float4*)&Cb[(size_t)(ty * 4 + r) * ldc] = v;
  }
}

// ---------------- mm_nt: A[64,K]@B^T (B [N,K] rows) (proven R7) ----------------
__device__ __forceinline__ void mm_nt_slice(
    const float* __restrict__ A, int lda, const float* __restrict__ B, int ldb,
    float* __restrict__ Cp, int ldc, int n_t, int k_t, float* smem) {
  float* As = smem;
  float* Bs = smem + 4096;
  int tid = threadIdx.x;
  int n0 = n_t * 64, k0 = k_t * 64;
  {
    int m  = tid >> 2;
    int kb = (tid & 3) * 16;
    const float* Ap = A + (size_t)m * lda + k0 + kb;
    const float* Bp = B + (size_t)(n0 + m) * ldb + k0 + kb;
    #pragma unroll
    for (int q = 0; q < 4; ++q) {
      float4 va = *(const float4*)(Ap + q * 4);
      As[(kb + q*4 + 0)*64 + m] = va.x;
      As[(kb + q*4 + 1)*64 + m] = va.y;
      As[(kb + q*4 + 2)*64 + m] = va.z;
      As[(kb + q*4 + 3)*64 + m] = va.w;
      float4 vb = *(const float4*)(Bp + q * 4);
      Bs[(kb + q*4 + 0)*64 + m] = vb.x;
      Bs[(kb + q*4 + 1)*64 + m] = vb.y;
      Bs[(kb + q*4 + 2)*64 + m] = vb.z;
      Bs[(kb + q*4 + 3)*64 + m] = vb.w;
    }
  }
  __syncthreads();
  int tx = tid & 15, ty = tid >> 4;
  float acc[4][4] = {{0.f}};
  #pragma unroll 16
  for (int kk = 0; kk < 64; ++kk) {
    float4 a = *(const float4*)&As[kk*64 + ty * 4];
    float4 b = *(const float4*)&Bs[kk*64 + tx * 4];
    MICRO_4x4
  }
  float* Cb = Cp + (size_t)k_t * 64 * ldc + n0 + tx * 4;
  #pragma unroll
  for (int r = 0; r < 4; ++r) {
    float4 v = { acc[r][0], acc[r][1], acc[r][2], acc[r][3] };
    *(float4*)&Cb[(size_t)(ty * 4 + r) * ldc] = v;
  }
}

// ---------------- upd64: Cnew = Cold - A^T B (proven R3/R7) ----------------
__device__ __forceinline__ void upd64_dev(
    const float* __restrict__ A, int P,
    const float* __restrict__ B, int Q,
    const float* __restrict__ Cold, float* __restrict__ Cnew,
    int bx, int by, float* smem) {
  float* As = smem;
  float* Bs = smem + 4096;
  int tid = threadIdx.x;
  int q0 = bx * 64;
  int p0 = by * 64;
  {
    int i = tid >> 4;
    int c = (tid & 15) * 4;
    #pragma unroll
    for (int q = 0; q < 4; ++q) {
      *(float4*)&As[(i + q*16)*64 + c] = *(const float4*)(A + (size_t)(i + q*16) * P + p0 + c);
      *(float4*)&Bs[(i + q*16)*64 + c] = *(const float4*)(B + (size_t)(i + q*16) * Q + q0 + c);
    }
  }
  __syncthreads();
  int tx = tid & 15, ty = tid >> 4;
  float acc[4][4] = {{0.f}};
  #pragma unroll 16
  for (int i = 0; i < 64; ++i) {
    float4 a = *(const float4*)&As[i*64 + ty * 4];
    float4 b = *(const float4*)&Bs[i*64 + tx * 4];
    MICRO_4x4
  }
  #pragma unroll
  for (int r = 0; r < 4; ++r) {
    size_t off = (size_t)(p0 + ty*4 + r) * Q + q0 + tx*4;
    float4 co = *(const float4*)&Cold[off];
    float4 v = { co.x - acc[r][0], co.y - acc[r][1], co.z - acc[r][2], co.w - acc[r][3] };
    *(float4*)&Cnew[off] = v;
  }
}

// ---------------- kk_slice / hb_slice (proven R7, short blocks) ----------------
__device__ __forceinline__ void kk_slice(int p, int s, const float* __restrict__ nk,
                                         float* __restrict__ KKsl, float* smem) {
  float* As = smem;
  float* Bs = smem + 4096;
  int tid = threadIdx.x;
  int c = 0;
  while ((c + 1) * (c + 2) / 2 <= p) ++c;
  int j = p - c * (c + 1) / 2;
  const float* A = nk + (size_t)c * 64 * DM;
  const float* B = nk + (size_t)j * 64 * DM;
  int k0 = s * 64;
  {
    int m  = tid >> 2;
    int kb = (tid & 3) * 16;
    const float* Ap = A + (size_t)m * DM + k0 + kb;
    const float* Bp = B + (size_t)m * DM + k0 + kb;
    #pragma unroll
    for (int q = 0; q < 4; ++q) {
      float4 va = *(const float4*)(Ap + q * 4);
      As[(kb + q*4 + 0)*64 + m] = va.x;
      As[(kb + q*4 + 1)*64 + m] = va.y;
      As[(kb + q*4 + 2)*64 + m] = va.z;
      As[(kb + q*4 + 3)*64 + m] = va.w;
      float4 vb = *(const float4*)(Bp + q * 4);
      Bs[(kb + q*4 + 0)*64 + m] = vb.x;
      Bs[(kb + q*4 + 1)*64 + m] = vb.y;
      Bs[(kb + q*4 + 2)*64 + m] = vb.z;
      Bs[(kb + q*4 + 3)*64 + m] = vb.w;
    }
  }
  __syncthreads();
  int tx = tid & 15, ty = tid >> 4;
  float acc[4][4] = {{0.f}};
  #pragma unroll 16
  for (int kk = 0; kk < 64; ++kk) {
    float4 a = *(const float4*)&As[kk*64 + ty * 4];
    float4 b = *(const float4*)&Bs[kk*64 + tx * 4];
    MICRO_4x4
  }
  float* dst = KKsl + ((size_t)p * 49 + s) * 4096;
  #pragma unroll
  for (int r = 0; r < 4; ++r) {
    float4 v = { acc[r][0], acc[r][1], acc[r][2], acc[r][3] };
    *(float4*)&dst[(ty*4 + r) * 64 + tx*4] = v;
  }
}

__device__ __forceinline__ void hb_slice(int jb, const float* __restrict__ nkA,
                                         const float* __restrict__ W1,
                                         float* __restrict__ Hb_sl, float* smem) {
  float* As = smem;
  float* Bs = smem + 4096;
  int tid = threadIdx.x;
  int s  = jb % 49;
  int nt = (jb / 49) % 8;
  int mt = jb / 392;
  int n0 = nt * 64;
  int m0 = mt * 64;
  int k0 = s * 64;
  {
    int m  = tid >> 2;
    int kb = (tid & 3) * 16;
    const float* Ap = nkA + (size_t)(m0 + m) * DM + k0 + kb;
    #pragma unroll
    for (int q = 0; q < 4; ++q) {
      float4 v = *(const float4*)(Ap + q * 4);
      As[(kb + q*4 + 0)*64 + m] = v.x;
      As[(kb + q*4 + 1)*64 + m] = v.y;
      As[(kb + q*4 + 2)*64 + m] = v.z;
      As[(kb + q*4 + 3)*64 + m] = v.w;
    }
    int kr = tid >> 4;
    int nn = (tid & 15) * 4;
    #pragma unroll
    for (int q = 0; q < 4; ++q)
      *(float4*)&Bs[(kr + q*16)*64 + nn] = *(const float4*)(W1 + (size_t)(k0 + kr + q*16) * DH + n0 + nn);
  }
  __syncthreads();
  int tx = tid & 15, ty = tid >> 4;
  float acc[4][4] = {{0.f}};
  #pragma unroll 16
  for (int kk = 0; kk < 64; ++kk) {
    float4 a = *(const float4*)&As[kk*64 + ty * 4];
    float4 b = *(const float4*)&Bs[kk*64 + tx * 4];
    MICRO_4x4
  }
  float* dst = Hb_sl + (size_t)s * 262144;
  #pragma unroll
  for (int r = 0; r < 4; ++r) {
    float4 v = { acc[r][0], acc[r][1], acc[r][2], acc[r][3] };
    *(float4*)&dst[(size_t)(m0 + ty*4 + r) * 512 + n0 + tx*4] = v;
  }
}

__global__ __launch_bounds__(256) void u1_kernel(
    const float* __restrict__ nk, const float* __restrict__ W1,
    float* __restrict__ KKsl, float* __restrict__ Hb_sl) {
  __shared__ float smem[8192];
  int job = blockIdx.x;
  if (job < 1764) kk_slice(job / 49, job % 49, nk, KKsl, smem);
  else            hb_slice(job - 1764, nk, W1, Hb_sl, smem);
}

__global__ __launch_bounds__(256) void u2_kernel(
    const float* __restrict__ KKsl, const float* __restrict__ Hb_sl,
    float* __restrict__ KKf, float* __restrict__ Hbase) {
  int i = blockIdx.x * 256 + threadIdx.x;
  if (i < 147456) {
    int pair = i >> 12, e = i & 4095;
    float s = 0.f;
    for (int t = 0; t < 49; ++t) s += KKsl[((size_t)pair * 49 + t) * 4096 + e];
    KKf[i] = s;
  } else {
    int j = i - 147456;   // < 262144
    float s = 0.f;
    for (int t = 0; t < 49; ++t) s += Hb_sl[(size_t)t * 262144 + j];
    Hbase[j] = s;
  }
}

// ---------------- hred ----------------
__device__ __forceinline__ void hred_body(
    int j, const float* __restrict__ Hb_c, const float* __restrict__ Hcorr, int nsl,
    const float* __restrict__ b1v,
    float* __restrict__ H, float* __restrict__ G, float* __restrict__ Gp) {
  float s = Hb_c[j];
  for (int t = 0; t < nsl; ++t) s -= Hcorr[(size_t)t * 32768 + j];
  H[j] = s;
  float g, gp;
  gelu_both(s + b1v[j & 511], g, gp);
  G[j] = g; Gp[j] = gp;
}

__global__ __launch_bounds__(256) void hred0_kernel(
    const float* __restrict__ Hbase, const float* __restrict__ b1,
    float* __restrict__ H, float* __restrict__ G, float* __restrict__ Gp) {
  int j = blockIdx.x * 256 + threadIdx.x;
  hred_body(j, Hbase, (const float*)nullptr, 0, b1, H, G, Gp);
}

// ---------------- hs_corr / gelu2k jobs (proven R7) ----------------
__device__ __forceinline__ void hs_corr_job(
    const float* __restrict__ KK, const float* __restrict__ Ewj,
    float* __restrict__ dst, int bx, float* smem) {
  float* As = smem;
  float* Bs = smem + 4096;
  int tid = threadIdx.x;
  int n0 = bx * 64;
  {
    int m = tid >> 2, ib = (tid & 3) * 16;
    #pragma unroll
    for (int q = 0; q < 4; ++q) {
      float4 v = *(const float4*)(KK + m * 64 + ib + q * 4);
      As[(ib + q*4 + 0)*64 + m] = v.x;
      As[(ib + q*4 + 1)*64 + m] = v.y;
      As[(ib + q*4 + 2)*64 + m] = v.z;
      As[(ib + q*4 + 3)*64 + m] = v.w;
    }
    int kr = tid >> 4, nn = (tid & 15) * 4;
    #pragma unroll
    for (int q = 0; q < 4; ++q)
      *(float4*)&Bs[(kr + q*16)*64 + nn] = *(const float4*)(Ewj + (size_t)(kr + q*16) * DH + n0 + nn);
  }
  __syncthreads();
  int tx = tid & 15, ty = tid >> 4;
  float acc[4][4] = {{0.f}};
  #pragma unroll 16
  for (int kk = 0; kk < 64; ++kk) {
    float4 a = *(const float4*)&As[kk*64 + ty * 4];
    float4 b = *(const float4*)&Bs[kk*64 + tx * 4];
    MICRO_4x4
  }
  #pragma unroll
  for (int r = 0; r < 4; ++r) {
    float4 v = { acc[r][0], acc[r][1], acc[r][2], acc[r][3] };
    *(float4*)&dst[(ty*4 + r) * DH + n0 + tx*4] = v;
  }
}

__device__ __forceinline__ void gelu2k_job(
    const float* __restrict__ KKcc, const float* __restrict__ Ew,
    const float* __restrict__ H, const float* __restrict__ b1n,
    float* __restrict__ G2, int n0, float* smem) {
  float* KKs = smem;
  float* Ews = smem + 4096;
  int tid = threadIdx.x;
  #pragma unroll
  for (int q = 0; q < 4; ++q) {
    int e4 = q * 256 + tid;
    *(float4*)&KKs[e4 * 4] = *(const float4*)(KKcc + e4 * 4);
  }
  {
    int i = tid >> 2, c4 = (tid & 3) * 4;
    *(float4*)&Ews[i * 16 + c4] = *(const float4*)(Ew + (size_t)i * DH + n0 + c4);
  }
  __syncthreads();
  #pragma unroll
  for (int q = 0; q < 4; ++q) {
    int e = q * 256 + tid;
    int mrow = e >> 4, cc = e & 15;
    float corr = 0.f;
    #pragma unroll 16
    for (int i = 0; i < 64; ++i) corr += KKs[mrow * 64 + i] * Ews[i * 16 + cc];
    float xx = H[mrow * DH + n0 + cc] - corr + b1n[n0 + cc];
    G2[mrow * DH + n0 + cc] = gelu_only(xx);
  }
}

// ================= per-chunk pipeline kernels =================
// P3 for chunk 0 (upfront): pred slices = G @ W2
__global__ __launch_bounds__(256) void p3_kernel(
    const float* __restrict__ G, const float* __restrict__ W2c,
    float* __restrict__ Spred) {
  __shared__ float smem[8192];
  mm_nn_slice(G, DH, W2c, DM, Spred, DM, blockIdx.x % 49, blockIdx.x / 49, smem);
}

// kA: Dw = wc2*(pred_sum + b2 - V); b2ws update (proven R7)
__global__ __launch_bounds__(256) void red_Db2(
    const float* __restrict__ Dp, const float* __restrict__ b2c,
    const float* __restrict__ V, float wc2,
    float* __restrict__ Dw, float* __restrict__ b2n) {
  __shared__ float sm[256];
  int tid = threadIdx.x;
  int col = blockIdx.x * 64 + (tid & 63);
  int r0 = (tid >> 6) * 16;
  float bb = b2c[col];
  float cs = 0.f;
  for (int rr = 0; rr < 16; ++rr) {
    size_t off = (size_t)(r0 + rr) * DM + col;
    float s = 0.f;
    #pragma unroll
    for (int t = 0; t < 8; ++t) s += Dp[(size_t)t * 200704 + off];
    float d = wc2 * (s + bb - V[off]);
    Dw[off] = d;
    cs += d;
  }
  sm[tid] = cs;
  __syncthreads();
  if (tid < 64) {
    float tot = sm[tid] + sm[tid + 64] + sm[tid + 128] + sm[tid + 192];
    b2n[blockIdx.x * 64 + tid] = b2c[blockIdx.x * 64 + tid] - tot;
  }
}

// kB: P4 E-slices (392) || W2n = W2c - G^T Dw (392)
__global__ __launch_bounds__(256) void p4w2_kernel(
    const float* __restrict__ Dw, const float* __restrict__ W2c,
    const float* __restrict__ G, float* __restrict__ SpE,
    float* __restrict__ W2n) {
  __shared__ float smem[8192];
  int b = blockIdx.x;
  if (b < 392) mm_nt_slice(Dw, DM, W2c, DM, SpE, DH, b & 7, b >> 3, smem);
  else {
    int li = b - 392;
    upd64_dev(G, DH, Dw, DM, W2c, W2n, li % 49, li / 49, smem);
  }
}

// kC: Ew = E_sum * Gp; b1ws update (proven R7)
__global__ __launch_bounds__(256) void ewb1_kernel(
    const float* __restrict__ Esl, const float* __restrict__ Gp,
    float* __restrict__ Ew, const float* __restrict__ b1old, float* __restrict__ b1new) {
  __shared__ float smem[256];
  int tid = threadIdx.x;
  int n0 = blockIdx.x * 4;
  int row = tid >> 2, c = tid & 3;
  int col = n0 + c;
  float s = 0.f;
  #pragma unroll
  for (int sl = 0; sl < 49; ++sl) s += Esl[(size_t)sl * 32768 + row * 512 + col];
  float ew = s * Gp[row * 512 + col];
  Ew[row * 512 + col] = ew;
  smem[tid] = ew;
  __syncthreads();
  for (int off = 128; off >= 4; off >>= 1) {
    if (tid < off) smem[tid] += smem[tid + off];
    __syncthreads();
  }
  if (tid < 4) b1new[n0 + tid] = b1old[n0 + tid] - smem[tid];
}

// kD: G2 = gelu(H - KK[c,c]@Ew + b1ws) (32) || Hcorr j=ch for chunk ch+1 (8, if ch<7)
__global__ __launch_bounds__(256) void g2s_kernel(
    const float* __restrict__ KKf, int tri, int ch,
    const float* __restrict__ Ewst, const float* __restrict__ H,
    const float* __restrict__ b1n,
    float* __restrict__ G2, float* __restrict__ Hcorr) {
  __shared__ float smem[8192];
  int b = blockIdx.x;
  if (b < 32) {
    gelu2k_job(KKf + (size_t)(tri + ch) * 4096, Ewst + (size_t)ch * 32768,
               H, b1n, G2, b * 16, smem);
  } else {
    int bx = b - 32;
    int trin = (ch + 1) * (ch + 2) / 2;
    hs_corr_job(KKf + (size_t)(trin + ch) * 4096, Ewst + (size_t)ch * 32768,
                Hcorr + (size_t)ch * 32768, bx, smem);
  }
}

// kE: P7 Y-slices (392) || hred for chunk ch+1 (128, if ch<7)
__global__ __launch_bounds__(256) void p7h_kernel(
    const float* __restrict__ G2, const float* __restrict__ W2n,
    float* __restrict__ SpY,
    const float* __restrict__ Hbase_n, const float* __restrict__ Hcorr, int nsl,
    const float* __restrict__ b1n,
    float* __restrict__ H, float* __restrict__ Gnext, float* __restrict__ Gp) {
  __shared__ float smem[8192];
  int b = blockIdx.x;
  if (b < 392) {
    mm_nn_slice(G2, DH, W2n, DM, SpY, DM, b % 49, b / 49, smem);
  } else {
    int j = (b - 392) * 256 + threadIdx.x;   // < 32768
    hred_body(j, Hbase_n, Hcorr, nsl, b1n, H, Gnext, Gp);
  }
}

// kF: out rows (784) || P3 for chunk ch+1 (392, if ch<7)
//     || Hcorr slices for chunk ch+2, j<ch+1 (8*(ch+1), if ch<6)
__global__ __launch_bounds__(256) void redyp3_kernel(
    const float* __restrict__ SpY, const float* __restrict__ b2n,
    float* __restrict__ out, int t0,
    const float* __restrict__ Gnext, const float* __restrict__ W2n,
    float* __restrict__ Spred,
    const float* __restrict__ KKf, int ch,
    const float* __restrict__ Ewst, float* __restrict__ Hcorr) {
  __shared__ float smem[8192];
  int b = blockIdx.x;
  int tid = threadIdx.x;
  if (b < 784) {
    int j = b * 256 + tid;
    float s = 0.f;
    #pragma unroll
    for (int t = 0; t < 8; ++t) s += SpY[(size_t)t * 200704 + j];
    int i = j / DM;
    int d = j - i * DM;
    out[(size_t)t0 * DM + j] = s + b2n[d];
  } else if (b < 1176) {
    int b2 = b - 784;
    mm_nn_slice(Gnext, DH, W2n, DM, Spred, DM, b2 % 49, b2 / 49, smem);
  } else {
    int j2 = b - 1176;                 // < 8*(ch+1)
    int j = j2 >> 3, bx = j2 & 7;      // j <= ch
    int cn2 = ch + 2;
    int trin = cn2 * (cn2 + 1) / 2;
    hs_corr_job(KKf + (size_t)(trin + j) * 4096, Ewst + (size_t)j * 32768,
                Hcorr + (size_t)j * 32768, bx, smem);
  }
}

extern "C" void kernel_launch(void* const* d_in, const int* in_sizes, int n_in,
                              void* d_out, int out_size, void* d_ws, size_t ws_size,
                              hipStream_t stream) {
  const float* x  = (const float*)d_in[0];
  const float* wk = (const float*)d_in[1];
  const float* bk = (const float*)d_in[2];
  const float* wv = (const float*)d_in[3];
  const float* bv = (const float*)d_in[4];
  const float* sk = (const float*)d_in[5];
  const float* sv = (const float*)d_in[6];
  const float* W1 = (const float*)d_in[7];
  const float* b1 = (const float*)d_in[8];
  const float* W2 = (const float*)d_in[9];
  const float* b2 = (const float*)d_in[10];
  float* out = (float*)d_out;
  float* ws  = (float*)d_ws;

  // workspace layout (floats)
  float* nk    = ws;                       // 1,605,632
  float* nv    = nk + 1605632;             // 1,605,632
  float* W2A   = nv + 1605632;             // 1,605,632
  float* W2B   = W2A + 1605632;            // 1,605,632
  float* Spred = W2B + 1605632;            // 1,605,632 (pred slices; reused for E slices)
  float* SpY   = Spred + 1605632;          // 1,605,632 (Y slices)
  float* Hb_sl = SpY + 1605632;            // 12,845,056 (49 x 262144)
  float* KKsl  = Hb_sl + 12845056;         // 7,225,344 (36 x 49 x 4096)
  float* Hbase = KKsl + 7225344;           // 262,144
  float* KKf   = Hbase + 262144;           // 147,456
  float* Hh    = KKf + 147456;             // 32,768
  float* GA    = Hh + 32768;               // 32,768
  float* GB    = GA + 32768;               // 32,768
  float* Gp    = GB + 32768;               // 32,768
  float* Dw    = Gp + 32768;               // 200,704
  float* Ewst  = Dw + 200704;              // 262,144 (8 x 32768)
  float* Hcorr = Ewst + 262144;            // 229,376 (7 x 32768)
  float* b1ws  = Hcorr + 229376;           // 512
  float* b2ws  = b1ws + 512;               // 3,136
  float* W2buf[2] = { W2A, W2B };
  float* Gbuf[2]  = { GA, GB };

  // weights[i] = ETA0 * ALPHA^i * (ALPHA^63 / ALPHA^i) = ETA0 * ALPHA^63 (constant)
  float wc2 = 2.0f * (float)(0.1 * pow(0.9, 63.0));

  conv_rms<<<1568, 256, 0, stream>>>(x, wk, bk, wv, bv, sk, sv, nk, nv);
  u1_kernel<<<4900, 256, 0, stream>>>(nk, W1, KKsl, Hb_sl);
  u2_kernel<<<1600, 256, 0, stream>>>(KKsl, Hb_sl, KKf, Hbase);
  hred0_kernel<<<128, 256, 0, stream>>>(Hbase, b1, Hh, Gbuf[0], Gp);
  p3_kernel<<<392, 256, 0, stream>>>(Gbuf[0], W2, Spred);

  for (int ch = 0; ch < 8; ++ch) {
    const float* V   = nv + (size_t)ch * 200704;
    const float* b1c = ch ? b1ws : b1;
    const float* b2c = ch ? b2ws : b2;
    const float* W2c = ch ? W2buf[(ch - 1) & 1] : W2;
    float* W2n  = W2buf[ch & 1];
    float* Gcur = Gbuf[ch & 1];
    float* Gnxt = Gbuf[(ch + 1) & 1];
    float* Ewc  = Ewst + (size_t)ch * 32768;
    int tri = ch * (ch + 1) / 2;

    // kA: Dw + b2 update (pred slices already in Spred from kF of ch-1 / upfront)
    red_Db2<<<49, 256, 0, stream>>>(Spred, b2c, V, wc2, Dw, b2ws);
    // kB: E slices (into Spred, pred consumed) || W2n = W2c - G^T Dw
    p4w2_kernel<<<784, 256, 0, stream>>>(Dw, W2c, Gcur, Spred, W2n);
    // kC: Ew + b1 update
    ewb1_kernel<<<128, 256, 0, stream>>>(Spred, Gp, Ewc, b1c, b1ws);
    // kD: G2 (overwrites Gcur) || Hcorr j=ch for chunk ch+1
    g2s_kernel<<<32 + (ch < 7 ? 8 : 0), 256, 0, stream>>>(
        KKf, tri, ch, Ewst, Hh, b1ws, Gcur, Hcorr);
    // kE: P7 Y-slices || hred for chunk ch+1 (writes Hh, Gnxt, Gp)
    p7h_kernel<<<392 + (ch < 7 ? 128 : 0), 256, 0, stream>>>(
        Gcur, W2n, SpY,
        Hbase + (size_t)(ch + 1) * 32768, Hcorr, ch + 1, b1ws, Hh, Gnxt, Gp);
    // kF: out rows || P3 for chunk ch+1 || Hcorr for chunk ch+2 (j<=ch)
    int gF = 784 + (ch < 7 ? 392 + (ch < 6 ? 8 * (ch + 1) : 0) : 0);
    redyp3_kernel<<<gF, 256, 0, stream>>>(
        SpY, b2ws, out, ch * 64, Gnxt, W2n, Spred, KKf, ch, Ewst, Hcorr);
  }
}

// Round 12
// 539.104 us; speedup vs baseline: 2.4873x; 1.1192x over previous
//
#include <hip/hip_runtime.h>
#include <math.h>

#define DM 3136
#define DH 512

#define MICRO_4x4 \
    acc[0][0] += a.x*b.x; acc[0][1] += a.x*b.y; acc[0][2] += a.x*b.z; acc[0][3] += a.x*b.w; \
    acc[1][0] += a.y*b.x; acc[1][1] += a.y*b.y; acc[1][2] += a.y*b.z; acc[1][3] += a.y*b.w; \
    acc[2][0] += a.z*b.x; acc[2][1] += a.z*b.y; acc[2][2] += a.z*b.z; acc[2][3] += a.z*b.w; \
    acc[3][0] += a.w*b.x; acc[3][1] += a.w*b.y; acc[3][2] += a.w*b.z; acc[3][3] += a.w*b.w;

// ---------------- gelu ----------------
__device__ __forceinline__ void gelu_both(float xx, float& g, float& gp) {
  const float c = 0.7978845608028654f;
  const float a = 0.044715f;
  float x2 = xx * xx;
  float u = c * (xx + a * xx * x2);
  float t = tanhf(u);
  g  = 0.5f * xx * (1.f + t);
  gp = 0.5f * (1.f + t) + 0.5f * xx * (1.f - t * t) * c * (1.f + 3.f * a * x2);
}
__device__ __forceinline__ float gelu_only(float xx) {
  const float c = 0.7978845608028654f;
  const float a = 0.044715f;
  float u = c * (xx + a * xx * xx * xx);
  return 0.5f * xx * (1.f + tanhf(u));
}

// ---------------- conv3x3 + RMSNorm (proven R2) ----------------
__global__ __launch_bounds__(256) void conv_rms(
    const float* __restrict__ x,
    const float* __restrict__ wk, const float* __restrict__ bk,
    const float* __restrict__ wv, const float* __restrict__ bv,
    const float* __restrict__ sk, const float* __restrict__ sv,
    float* __restrict__ nk, float* __restrict__ nv) {
  __shared__ float swk[144], swv[144], sb[16];
  int tid = threadIdx.x;
  if (tid < 144) { swk[tid] = wk[tid]; swv[tid] = wv[tid]; }
  if (tid < 4) {
    sb[tid] = bk[tid]; sb[4 + tid] = bv[tid];
    sb[8 + tid] = sk[tid]; sb[12 + tid] = sv[tid];
  }
  __syncthreads();
  int idx = blockIdx.x * 256 + tid;
  int t = idx / 784, hw = idx - t * 784;
  int h = hw / 28, w = hw - h * 28;
  float ak[4], av[4];
  #pragma unroll
  for (int c = 0; c < 4; ++c) { ak[c] = sb[c]; av[c] = sb[4 + c]; }
  const float* xt = x + (size_t)t * DM;
  for (int kh = 0; kh < 3; ++kh) {
    int ih = h + kh - 1;
    if (ih < 0 || ih >= 28) continue;
    for (int kw = 0; kw < 3; ++kw) {
      int iw = w + kw - 1;
      if (iw < 0 || iw >= 28) continue;
      int base = (kh * 3 + kw) * 16;
      #pragma unroll
      for (int ci = 0; ci < 4; ++ci) {
        float xv = xt[ci * 784 + ih * 28 + iw];
        #pragma unroll
        for (int co = 0; co < 4; ++co) {
          ak[co] += xv * swk[base + ci * 4 + co];
          av[co] += xv * swv[base + ci * 4 + co];
        }
      }
    }
  }
  float mk = (ak[0]*ak[0] + ak[1]*ak[1] + ak[2]*ak[2] + ak[3]*ak[3]) * 0.25f + 1e-6f;
  float mv = (av[0]*av[0] + av[1]*av[1] + av[2]*av[2] + av[3]*av[3]) * 0.25f + 1e-6f;
  float ik = 1.f / sqrtf(mk), iv = 1.f / sqrtf(mv);
  float4 ok = { ak[0]*ik*sb[8],  ak[1]*ik*sb[9],  ak[2]*ik*sb[10], ak[3]*ik*sb[11] };
  float4 ov = { av[0]*iv*sb[12], av[1]*iv*sb[13], av[2]*iv*sb[14], av[3]*iv*sb[15] };
  *(float4*)&nk[(size_t)idx * 4] = ok;
  *(float4*)&nv[(size_t)idx * 4] = ov;
}

// ---------------- mm_nn: A[64,K]@B tile -> slice (proven R7) ----------------
__device__ __forceinline__ void mm_nn_slice(
    const float* __restrict__ A, int lda, const float* __restrict__ B, int ldb,
    float* __restrict__ Cp, int ldc, int n_t, int k_t, float* smem) {
  float* As = smem;
  float* Bs = smem + 4096;
  int tid = threadIdx.x;
  int n0 = n_t * 64, k0 = k_t * 64;
  {
    int m  = tid >> 2;
    int kb = (tid & 3) * 16;
    const float* Ap = A + (size_t)m * lda + k0 + kb;
    #pragma unroll
    for (int q = 0; q < 4; ++q) {
      float4 v = *(const float4*)(Ap + q * 4);
      As[(kb + q*4 + 0)*64 + m] = v.x;
      As[(kb + q*4 + 1)*64 + m] = v.y;
      As[(kb + q*4 + 2)*64 + m] = v.z;
      As[(kb + q*4 + 3)*64 + m] = v.w;
    }
    int kr = tid >> 4;
    int nn = (tid & 15) * 4;
    #pragma unroll
    for (int q = 0; q < 4; ++q)
      *(float4*)&Bs[(kr + q*16)*64 + nn] = *(const float4*)(B + (size_t)(k0 + kr + q*16) * ldb + n0 + nn);
  }
  __syncthreads();
  int tx = tid & 15, ty = tid >> 4;
  float acc[4][4] = {{0.f}};
  #pragma unroll 16
  for (int kk = 0; kk < 64; ++kk) {
    float4 a = *(const float4*)&As[kk*64 + ty * 4];
    float4 b = *(const float4*)&Bs[kk*64 + tx * 4];
    MICRO_4x4
  }
  float* Cb = Cp + (size_t)k_t * 64 * ldc + n0 + tx * 4;
  #pragma unroll
  for (int r = 0; r < 4; ++r) {
    float4 v = { acc[r][0], acc[r][1], acc[r][2], acc[r][3] };
    *(float4*)&Cb[(size_t)(ty * 4 + r) * ldc] = v;
  }
}

// ---------------- mm_nt: A[64,K]@B^T (B [N,K] rows) (proven R7) ----------------
__device__ __forceinline__ void mm_nt_slice(
    const float* __restrict__ A, int lda, const float* __restrict__ B, int ldb,
    float* __restrict__ Cp, int ldc, int n_t, int k_t, float* smem) {
  float* As = smem;
  float* Bs = smem + 4096;
  int tid = threadIdx.x;
  int n0 = n_t * 64, k0 = k_t * 64;
  {
    int m  = tid >> 2;
    int kb = (tid & 3) * 16;
    const float* Ap = A + (size_t)m * lda + k0 + kb;
    const float* Bp = B + (size_t)(n0 + m) * ldb + k0 + kb;
    #pragma unroll
    for (int q = 0; q < 4; ++q) {
      float4 va = *(const float4*)(Ap + q * 4);
      As[(kb + q*4 + 0)*64 + m] = va.x;
      As[(kb + q*4 + 1)*64 + m] = va.y;
      As[(kb + q*4 + 2)*64 + m] = va.z;
      As[(kb + q*4 + 3)*64 + m] = va.w;
      float4 vb = *(const float4*)(Bp + q * 4);
      Bs[(kb + q*4 + 0)*64 + m] = vb.x;
      Bs[(kb + q*4 + 1)*64 + m] = vb.y;
      Bs[(kb + q*4 + 2)*64 + m] = vb.z;
      Bs[(kb + q*4 + 3)*64 + m] = vb.w;
    }
  }
  __syncthreads();
  int tx = tid & 15, ty = tid >> 4;
  float acc[4][4] = {{0.f}};
  #pragma unroll 16
  for (int kk = 0; kk < 64; ++kk) {
    float4 a = *(const float4*)&As[kk*64 + ty * 4];
    float4 b = *(const float4*)&Bs[kk*64 + tx * 4];
    MICRO_4x4
  }
  float* Cb = Cp + (size_t)k_t * 64 * ldc + n0 + tx * 4;
  #pragma unroll
  for (int r = 0; r < 4; ++r) {
    float4 v = { acc[r][0], acc[r][1], acc[r][2], acc[r][3] };
    *(float4*)&Cb[(size_t)(ty * 4 + r) * ldc] = v;
  }
}

// ---------------- upd64: Cnew = Cold - A^T B (proven R3/R7) ----------------
__device__ __forceinline__ void upd64_dev(
    const float* __restrict__ A, int P,
    const float* __restrict__ B, int Q,
    const float* __restrict__ Cold, float* __restrict__ Cnew,
    int bx, int by, float* smem) {
  float* As = smem;
  float* Bs = smem + 4096;
  int tid = threadIdx.x;
  int q0 = bx * 64;
  int p0 = by * 64;
  {
    int i = tid >> 4;
    int c = (tid & 15) * 4;
    #pragma unroll
    for (int q = 0; q < 4; ++q) {
      *(float4*)&As[(i + q*16)*64 + c] = *(const float4*)(A + (size_t)(i + q*16) * P + p0 + c);
      *(float4*)&Bs[(i + q*16)*64 + c] = *(const float4*)(B + (size_t)(i + q*16) * Q + q0 + c);
    }
  }
  __syncthreads();
  int tx = tid & 15, ty = tid >> 4;
  float acc[4][4] = {{0.f}};
  #pragma unroll 16
  for (int i = 0; i < 64; ++i) {
    float4 a = *(const float4*)&As[i*64 + ty * 4];
    float4 b = *(const float4*)&Bs[i*64 + tx * 4];
    MICRO_4x4
  }
  #pragma unroll
  for (int r = 0; r < 4; ++r) {
    size_t off = (size_t)(p0 + ty*4 + r) * Q + q0 + tx*4;
    float4 co = *(const float4*)&Cold[off];
    float4 v = { co.x - acc[r][0], co.y - acc[r][1], co.z - acc[r][2], co.w - acc[r][3] };
    *(float4*)&Cnew[off] = v;
  }
}

// ---------------- u1: pair-slice jobs (2 consecutive 64-k chunks per block) ----------------
__device__ __forceinline__ void kk_slice2(int p, int s2, const float* __restrict__ nk,
                                          float* __restrict__ KKsl, float* smem) {
  float* As = smem;
  float* Bs = smem + 4096;
  int tid = threadIdx.x;
  int c = 0;
  while ((c + 1) * (c + 2) / 2 <= p) ++c;
  int j = p - c * (c + 1) / 2;
  const float* A = nk + (size_t)c * 64 * DM;
  const float* B = nk + (size_t)j * 64 * DM;
  int m  = tid >> 2;
  int kb = (tid & 3) * 16;
  int tx = tid & 15, ty = tid >> 4;
  float acc[4][4] = {{0.f}};
  int nit = (s2 < 24) ? 2 : 1;        // 49 chunks: 24 pairs + 1 single
  for (int it = 0; it < nit; ++it) {
    int k0 = (s2 * 2 + it) * 64;
    const float* Ap = A + (size_t)m * DM + k0 + kb;
    const float* Bp = B + (size_t)m * DM + k0 + kb;
    #pragma unroll
    for (int q = 0; q < 4; ++q) {
      float4 va = *(const float4*)(Ap + q * 4);
      As[(kb + q*4 + 0)*64 + m] = va.x;
      As[(kb + q*4 + 1)*64 + m] = va.y;
      As[(kb + q*4 + 2)*64 + m] = va.z;
      As[(kb + q*4 + 3)*64 + m] = va.w;
      float4 vb = *(const float4*)(Bp + q * 4);
      Bs[(kb + q*4 + 0)*64 + m] = vb.x;
      Bs[(kb + q*4 + 1)*64 + m] = vb.y;
      Bs[(kb + q*4 + 2)*64 + m] = vb.z;
      Bs[(kb + q*4 + 3)*64 + m] = vb.w;
    }
    __syncthreads();
    #pragma unroll 16
    for (int kk = 0; kk < 64; ++kk) {
      float4 a = *(const float4*)&As[kk*64 + ty * 4];
      float4 b = *(const float4*)&Bs[kk*64 + tx * 4];
      MICRO_4x4
    }
    __syncthreads();
  }
  float* dst = KKsl + ((size_t)p * 25 + s2) * 4096;
  #pragma unroll
  for (int r = 0; r < 4; ++r) {
    float4 v = { acc[r][0], acc[r][1], acc[r][2], acc[r][3] };
    *(float4*)&dst[(ty*4 + r) * 64 + tx*4] = v;
  }
}

__device__ __forceinline__ void hb_slice2(int jb, const float* __restrict__ nkA,
                                          const float* __restrict__ W1,
                                          float* __restrict__ Hb_sl, float* smem) {
  float* As = smem;
  float* Bs = smem + 4096;
  int tid = threadIdx.x;
  int s2 = jb % 25;
  int nt = (jb / 25) % 8;
  int mt = jb / 200;
  int n0 = nt * 64;
  int m0 = mt * 64;
  int m  = tid >> 2;
  int kb = (tid & 3) * 16;
  int kr = tid >> 4;
  int nn = (tid & 15) * 4;
  int tx = tid & 15, ty = tid >> 4;
  float acc[4][4] = {{0.f}};
  int nit = (s2 < 24) ? 2 : 1;
  for (int it = 0; it < nit; ++it) {
    int k0 = (s2 * 2 + it) * 64;
    const float* Ap = nkA + (size_t)(m0 + m) * DM + k0 + kb;
    #pragma unroll
    for (int q = 0; q < 4; ++q) {
      float4 v = *(const float4*)(Ap + q * 4);
      As[(kb + q*4 + 0)*64 + m] = v.x;
      As[(kb + q*4 + 1)*64 + m] = v.y;
      As[(kb + q*4 + 2)*64 + m] = v.z;
      As[(kb + q*4 + 3)*64 + m] = v.w;
      *(float4*)&Bs[(kr + q*16)*64 + nn] = *(const float4*)(W1 + (size_t)(k0 + kr + q*16) * DH + n0 + nn);
    }
    __syncthreads();
    #pragma unroll 16
    for (int kk = 0; kk < 64; ++kk) {
      float4 a = *(const float4*)&As[kk*64 + ty * 4];
      float4 b = *(const float4*)&Bs[kk*64 + tx * 4];
      MICRO_4x4
    }
    __syncthreads();
  }
  float* dst = Hb_sl + (size_t)s2 * 262144;
  #pragma unroll
  for (int r = 0; r < 4; ++r) {
    float4 v = { acc[r][0], acc[r][1], acc[r][2], acc[r][3] };
    *(float4*)&dst[(size_t)(m0 + ty*4 + r) * 512 + n0 + tx*4] = v;
  }
}

__global__ __launch_bounds__(256) void u1_kernel(
    const float* __restrict__ nk, const float* __restrict__ W1,
    float* __restrict__ KKsl, float* __restrict__ Hb_sl) {
  __shared__ float smem[8192];
  int job = blockIdx.x;
  if (job < 900) kk_slice2(job / 25, job % 25, nk, KKsl, smem);
  else           hb_slice2(job - 900, nk, W1, Hb_sl, smem);
}

// u2: KKf (sum 25) + Hbase (sum 25) + fused hred for chunk 0 (j<32768)
__global__ __launch_bounds__(256) void u2_kernel(
    const float* __restrict__ KKsl, const float* __restrict__ Hb_sl,
    float* __restrict__ KKf, float* __restrict__ Hbase,
    const float* __restrict__ b1,
    float* __restrict__ Hh, float* __restrict__ G, float* __restrict__ Gp) {
  int i = blockIdx.x * 256 + threadIdx.x;
  if (i < 147456) {
    int pair = i >> 12, e = i & 4095;
    float s = 0.f;
    #pragma unroll
    for (int t = 0; t < 25; ++t) s += KKsl[((size_t)pair * 25 + t) * 4096 + e];
    KKf[i] = s;
  } else {
    int j = i - 147456;   // < 262144
    float s = 0.f;
    #pragma unroll
    for (int t = 0; t < 25; ++t) s += Hb_sl[(size_t)t * 262144 + j];
    Hbase[j] = s;
    if (j < 32768) {      // chunk 0 rows: emit H/G/Gp directly
      Hh[j] = s;
      float g, gp;
      gelu_both(s + b1[j & 511], g, gp);
      G[j] = g; Gp[j] = gp;
    }
  }
}

// ---------------- hred ----------------
__device__ __forceinline__ void hred_body(
    int j, const float* __restrict__ Hb_c, const float* __restrict__ Hcorr, int nsl,
    const float* __restrict__ b1v,
    float* __restrict__ H, float* __restrict__ G, float* __restrict__ Gp) {
  float s = Hb_c[j];
  for (int t = 0; t < nsl; ++t) s -= Hcorr[(size_t)t * 32768 + j];
  H[j] = s;
  float g, gp;
  gelu_both(s + b1v[j & 511], g, gp);
  G[j] = g; Gp[j] = gp;
}

// ---------------- hs_corr / gelu2k jobs (proven R7) ----------------
__device__ __forceinline__ void hs_corr_job(
    const float* __restrict__ KK, const float* __restrict__ Ewj,
    float* __restrict__ dst, int bx, float* smem) {
  float* As = smem;
  float* Bs = smem + 4096;
  int tid = threadIdx.x;
  int n0 = bx * 64;
  {
    int m = tid >> 2, ib = (tid & 3) * 16;
    #pragma unroll
    for (int q = 0; q < 4; ++q) {
      float4 v = *(const float4*)(KK + m * 64 + ib + q * 4);
      As[(ib + q*4 + 0)*64 + m] = v.x;
      As[(ib + q*4 + 1)*64 + m] = v.y;
      As[(ib + q*4 + 2)*64 + m] = v.z;
      As[(ib + q*4 + 3)*64 + m] = v.w;
    }
    int kr = tid >> 4, nn = (tid & 15) * 4;
    #pragma unroll
    for (int q = 0; q < 4; ++q)
      *(float4*)&Bs[(kr + q*16)*64 + nn] = *(const float4*)(Ewj + (size_t)(kr + q*16) * DH + n0 + nn);
  }
  __syncthreads();
  int tx = tid & 15, ty = tid >> 4;
  float acc[4][4] = {{0.f}};
  #pragma unroll 16
  for (int kk = 0; kk < 64; ++kk) {
    float4 a = *(const float4*)&As[kk*64 + ty * 4];
    float4 b = *(const float4*)&Bs[kk*64 + tx * 4];
    MICRO_4x4
  }
  #pragma unroll
  for (int r = 0; r < 4; ++r) {
    float4 v = { acc[r][0], acc[r][1], acc[r][2], acc[r][3] };
    *(float4*)&dst[(ty*4 + r) * DH + n0 + tx*4] = v;
  }
}

__device__ __forceinline__ void gelu2k_job(
    const float* __restrict__ KKcc, const float* __restrict__ Ew,
    const float* __restrict__ H, const float* __restrict__ b1n,
    float* __restrict__ G2, int n0, float* smem) {
  float* KKs = smem;
  float* Ews = smem + 4096;
  int tid = threadIdx.x;
  #pragma unroll
  for (int q = 0; q < 4; ++q) {
    int e4 = q * 256 + tid;
    *(float4*)&KKs[e4 * 4] = *(const float4*)(KKcc + e4 * 4);
  }
  {
    int i = tid >> 2, c4 = (tid & 3) * 4;
    *(float4*)&Ews[i * 16 + c4] = *(const float4*)(Ew + (size_t)i * DH + n0 + c4);
  }
  __syncthreads();
  #pragma unroll
  for (int q = 0; q < 4; ++q) {
    int e = q * 256 + tid;
    int mrow = e >> 4, cc = e & 15;
    float corr = 0.f;
    #pragma unroll 16
    for (int i = 0; i < 64; ++i) corr += KKs[mrow * 64 + i] * Ews[i * 16 + cc];
    float xx = H[mrow * DH + n0 + cc] - corr + b1n[n0 + cc];
    G2[mrow * DH + n0 + cc] = gelu_only(xx);
  }
}

// ================= per-chunk pipeline kernels =================
// P3 for chunk 0 (upfront)
__global__ __launch_bounds__(256) void p3_kernel(
    const float* __restrict__ G, const float* __restrict__ W2c,
    float* __restrict__ Spred) {
  __shared__ float smem[8192];
  mm_nn_slice(G, DH, W2c, DM, Spred, DM, blockIdx.x % 49, blockIdx.x / 49, smem);
}

// kA: Dw + partial colsums (49 n-tiles x 8 row-groups = 392 blocks)
__global__ __launch_bounds__(256) void red_Db2(
    const float* __restrict__ Dp, const float* __restrict__ b2c,
    const float* __restrict__ V, float wc2,
    float* __restrict__ Dw, float* __restrict__ Dcs) {
  __shared__ float sm[256];
  int tid = threadIdx.x;
  int nt = blockIdx.x % 49, rg = blockIdx.x / 49;
  int col = nt * 64 + (tid & 63);
  int r0 = rg * 8 + (tid >> 6) * 2;
  float bb = b2c[col];
  float cs = 0.f;
  #pragma unroll
  for (int rr = 0; rr < 2; ++rr) {
    size_t off = (size_t)(r0 + rr) * DM + col;
    float s = 0.f;
    #pragma unroll
    for (int t = 0; t < 8; ++t) s += Dp[(size_t)t * 200704 + off];
    float d = wc2 * (s + bb - V[off]);
    Dw[off] = d;
    cs += d;
  }
  sm[tid] = cs;
  __syncthreads();
  if (tid < 128) sm[tid] += sm[tid + 128];
  __syncthreads();
  if (tid < 64) Dcs[(size_t)rg * DM + col] = sm[tid] + sm[tid + 64];
}

// kB: P4 E-slices (392) || W2n = W2c - G^T Dw (392)
__global__ __launch_bounds__(256) void p4w2_kernel(
    const float* __restrict__ Dw, const float* __restrict__ W2c,
    const float* __restrict__ G, float* __restrict__ SpE,
    float* __restrict__ W2n) {
  __shared__ float smem[8192];
  int b = blockIdx.x;
  if (b < 392) mm_nt_slice(Dw, DM, W2c, DM, SpE, DH, b & 7, b >> 3, smem);
  else {
    int li = b - 392;
    upd64_dev(G, DH, Dw, DM, W2c, W2n, li % 49, li / 49, smem);
  }
}

// kC: Ew + b1 update (128) || b2 finalize from Dcs (49)
__global__ __launch_bounds__(256) void ewb1_kernel(
    const float* __restrict__ Esl, const float* __restrict__ Gp,
    float* __restrict__ Ew, const float* __restrict__ b1old, float* __restrict__ b1new,
    const float* __restrict__ Dcs, const float* __restrict__ b2c,
    float* __restrict__ b2n) {
  __shared__ float smem[256];
  int tid = threadIdx.x;
  int b = blockIdx.x;
  if (b < 128) {
    int n0 = b * 4;
    int row = tid >> 2, c = tid & 3;
    int col = n0 + c;
    float s = 0.f;
    #pragma unroll
    for (int sl = 0; sl < 49; ++sl) s += Esl[(size_t)sl * 32768 + row * 512 + col];
    float ew = s * Gp[row * 512 + col];
    Ew[row * 512 + col] = ew;
    smem[tid] = ew;
    __syncthreads();
    for (int off = 128; off >= 4; off >>= 1) {
      if (tid < off) smem[tid] += smem[tid + off];
      __syncthreads();
    }
    if (tid < 4) b1new[n0 + tid] = b1old[n0 + tid] - smem[tid];
  } else {
    int jb = b - 128;                 // < 49
    if (tid < 64) {
      int col = jb * 64 + tid;
      float s = 0.f;
      #pragma unroll
      for (int rg = 0; rg < 8; ++rg) s += Dcs[(size_t)rg * DM + col];
      b2n[col] = b2c[col] - s;
    }
  }
}

// kD: G2 (32) || Hcorr j=ch for chunk ch+1 (8, if ch<7)
__global__ __launch_bounds__(256) void g2s_kernel(
    const float* __restrict__ KKf, int tri, int ch,
    const float* __restrict__ Ewst, const float* __restrict__ H,
    const float* __restrict__ b1n,
    float* __restrict__ G2, float* __restrict__ Hcorr) {
  __shared__ float smem[8192];
  int b = blockIdx.x;
  if (b < 32) {
    gelu2k_job(KKf + (size_t)(tri + ch) * 4096, Ewst + (size_t)ch * 32768,
               H, b1n, G2, b * 16, smem);
  } else {
    int bx = b - 32;
    int trin = (ch + 1) * (ch + 2) / 2;
    hs_corr_job(KKf + (size_t)(trin + ch) * 4096, Ewst + (size_t)ch * 32768,
                Hcorr + (size_t)ch * 32768, bx, smem);
  }
}

// kE: P7 Y-slices (392) || hred for chunk ch+1 (128, if ch<7)
__global__ __launch_bounds__(256) void p7h_kernel(
    const float* __restrict__ G2, const float* __restrict__ W2n,
    float* __restrict__ SpY,
    const float* __restrict__ Hbase_n, const float* __restrict__ Hcorr, int nsl,
    const float* __restrict__ b1n,
    float* __restrict__ H, float* __restrict__ Gnext, float* __restrict__ Gp) {
  __shared__ float smem[8192];
  int b = blockIdx.x;
  if (b < 392) {
    mm_nn_slice(G2, DH, W2n, DM, SpY, DM, b % 49, b / 49, smem);
  } else {
    int j = (b - 392) * 256 + threadIdx.x;   // < 32768
    hred_body(j, Hbase_n, Hcorr, nsl, b1n, H, Gnext, Gp);
  }
}

// kF: out rows (784) || P3 for chunk ch+1 (392, if ch<7)
//     || Hcorr slices for chunk ch+2, j<ch+1 (8*(ch+1), if ch<6)
__global__ __launch_bounds__(256) void redyp3_kernel(
    const float* __restrict__ SpY, const float* __restrict__ b2n,
    float* __restrict__ out, int t0,
    const float* __restrict__ Gnext, const float* __restrict__ W2n,
    float* __restrict__ Spred,
    const float* __restrict__ KKf, int ch,
    const float* __restrict__ Ewst, float* __restrict__ Hcorr) {
  __shared__ float smem[8192];
  int b = blockIdx.x;
  int tid = threadIdx.x;
  if (b < 784) {
    int j = b * 256 + tid;
    float s = 0.f;
    #pragma unroll
    for (int t = 0; t < 8; ++t) s += SpY[(size_t)t * 200704 + j];
    int i = j / DM;
    int d = j - i * DM;
    out[(size_t)t0 * DM + j] = s + b2n[d];
  } else if (b < 1176) {
    int b2 = b - 784;
    mm_nn_slice(Gnext, DH, W2n, DM, Spred, DM, b2 % 49, b2 / 49, smem);
  } else {
    int j2 = b - 1176;                 // < 8*(ch+1)
    int j = j2 >> 3, bx = j2 & 7;      // j <= ch
    int cn2 = ch + 2;
    int trin = cn2 * (cn2 + 1) / 2;
    hs_corr_job(KKf + (size_t)(trin + j) * 4096, Ewst + (size_t)j * 32768,
                Hcorr + (size_t)j * 32768, bx, smem);
  }
}

extern "C" void kernel_launch(void* const* d_in, const int* in_sizes, int n_in,
                              void* d_out, int out_size, void* d_ws, size_t ws_size,
                              hipStream_t stream) {
  const float* x  = (const float*)d_in[0];
  const float* wk = (const float*)d_in[1];
  const float* bk = (const float*)d_in[2];
  const float* wv = (const float*)d_in[3];
  const float* bv = (const float*)d_in[4];
  const float* sk = (const float*)d_in[5];
  const float* sv = (const float*)d_in[6];
  const float* W1 = (const float*)d_in[7];
  const float* b1 = (const float*)d_in[8];
  const float* W2 = (const float*)d_in[9];
  const float* b2 = (const float*)d_in[10];
  float* out = (float*)d_out;
  float* ws  = (float*)d_ws;

  // workspace layout (floats)
  float* nk    = ws;                       // 1,605,632
  float* nv    = nk + 1605632;             // 1,605,632
  float* W2A   = nv + 1605632;             // 1,605,632
  float* W2B   = W2A + 1605632;            // 1,605,632
  float* Spred = W2B + 1605632;            // 1,605,632
  float* SpY   = Spred + 1605632;          // 1,605,632
  float* Hb_sl = SpY + 1605632;            // 6,553,600 (25 x 262144)
  float* KKsl  = Hb_sl + 6553600;          // 3,686,400 (36 x 25 x 4096)
  float* Hbase = KKsl + 3686400;           // 262,144
  float* KKf   = Hbase + 262144;           // 147,456
  float* Hh    = KKf + 147456;             // 32,768
  float* GA    = Hh + 32768;               // 32,768
  float* GB    = GA + 32768;               // 32,768
  float* Gp    = GB + 32768;               // 32,768
  float* Dw    = Gp + 32768;               // 200,704
  float* Dcs   = Dw + 200704;              // 25,088 (8 x 3136)
  float* Ewst  = Dcs + 25088;              // 262,144 (8 x 32768)
  float* Hcorr = Ewst + 262144;            // 229,376 (7 x 32768)
  float* b1ws  = Hcorr + 229376;           // 512
  float* b2ws  = b1ws + 512;               // 3,136
  float* W2buf[2] = { W2A, W2B };
  float* Gbuf[2]  = { GA, GB };

  // weights[i] = ETA0 * ALPHA^i * (ALPHA^63 / ALPHA^i) = ETA0 * ALPHA^63 (constant)
  float wc2 = 2.0f * (float)(0.1 * pow(0.9, 63.0));

  conv_rms<<<1568, 256, 0, stream>>>(x, wk, bk, wv, bv, sk, sv, nk, nv);
  u1_kernel<<<2500, 256, 0, stream>>>(nk, W1, KKsl, Hb_sl);
  u2_kernel<<<1600, 256, 0, stream>>>(KKsl, Hb_sl, KKf, Hbase, b1, Hh, Gbuf[0], Gp);
  p3_kernel<<<392, 256, 0, stream>>>(Gbuf[0], W2, Spred);

  for (int ch = 0; ch < 8; ++ch) {
    const float* V   = nv + (size_t)ch * 200704;
    const float* b1c = ch ? b1ws : b1;
    const float* b2c = ch ? b2ws : b2;
    const float* W2c = ch ? W2buf[(ch - 1) & 1] : W2;
    float* W2n  = W2buf[ch & 1];
    float* Gcur = Gbuf[ch & 1];
    float* Gnxt = Gbuf[(ch + 1) & 1];
    float* Ewc  = Ewst + (size_t)ch * 32768;
    int tri = ch * (ch + 1) / 2;

    // kA: Dw + partial colsums
    red_Db2<<<392, 256, 0, stream>>>(Spred, b2c, V, wc2, Dw, Dcs);
    // kB: E slices (into Spred) || W2n = W2c - G^T Dw
    p4w2_kernel<<<784, 256, 0, stream>>>(Dw, W2c, Gcur, Spred, W2n);
    // kC: Ew + b1 update || b2 finalize
    ewb1_kernel<<<177, 256, 0, stream>>>(Spred, Gp, Ewc, b1c, b1ws, Dcs, b2c, b2ws);
    // kD: G2 (overwrites Gcur) || Hcorr j=ch for chunk ch+1
    g2s_kernel<<<32 + (ch < 7 ? 8 : 0), 256, 0, stream>>>(
        KKf, tri, ch, Ewst, Hh, b1ws, Gcur, Hcorr);
    // kE: P7 Y-slices || hred for chunk ch+1
    p7h_kernel<<<392 + (ch < 7 ? 128 : 0), 256, 0, stream>>>(
        Gcur, W2n, SpY,
        Hbase + (size_t)(ch + 1) * 32768, Hcorr, ch + 1, b1ws, Hh, Gnxt, Gp);
    // kF: out rows || P3 for chunk ch+1 || Hcorr for chunk ch+2 (j<=ch)
    int gF = 784 + (ch < 7 ? 392 + (ch < 6 ? 8 * (ch + 1) : 0) : 0);
    redyp3_kernel<<<gF, 256, 0, stream>>>(
        SpY, b2ws, out, ch * 64, Gnxt, W2n, Spred, KKf, ch, Ewst, Hcorr);
  }
}